// Round 6
// baseline (215.679 us; speedup 1.0000x reference)
//
#include <hip/hip_runtime.h>
#include <cstdint>
#include <cstddef>

typedef _Float16 h8_t __attribute__((ext_vector_type(8)));
typedef _Float16 h4_t __attribute__((ext_vector_type(4)));
typedef float f32x4 __attribute__((ext_vector_type(4)));
typedef float f32x16 __attribute__((ext_vector_type(16)));
typedef unsigned u32x4 __attribute__((ext_vector_type(4)));

#define MFMA_16x16x32_F16(a, b, c) __builtin_amdgcn_mfma_f32_16x16x32_f16(a, b, c, 0, 0, 0)
#define MFMA_32x32x16_F16(a, b, c) __builtin_amdgcn_mfma_f32_32x32x16_f16(a, b, c, 0, 0, 0)

__device__ inline void gload_lds16(const void* g, void* l) {
  __builtin_amdgcn_global_load_lds((const __attribute__((address_space(1))) void*)g,
                                   (__attribute__((address_space(3))) void*)l, 16, 0, 0);
}

// ---------------- convert f32 -> f16 ----------------
__global__ void cvt_f16_kernel(const float* __restrict__ in, _Float16* __restrict__ out, int n4) {
  int i = blockIdx.x * 256 + threadIdx.x;
  if (i >= n4) return;
  float4 v = reinterpret_cast<const float4*>(in)[i];
  h4_t h;
  h[0] = (_Float16)v.x; h[1] = (_Float16)v.y; h[2] = (_Float16)v.z; h[3] = (_Float16)v.w;
  reinterpret_cast<h4_t*>(out)[i] = h;
}

// ---------------- transpose + convert: in[R][Cc] f32 -> out[Cc][R] f16 ----------------
__global__ void transpose_cvt_kernel(const float* __restrict__ in, _Float16* __restrict__ out,
                                     int R, int Cc) {
  __shared__ float tile[32][33];
  int tx = threadIdx.x & 31;
  int ty = threadIdx.x >> 5;
  int c0 = blockIdx.x * 32;
  int r0 = blockIdx.y * 32;
#pragma unroll
  for (int i = 0; i < 4; ++i)
    tile[ty + i * 8][tx] = in[(size_t)(r0 + ty + i * 8) * Cc + (c0 + tx)];
  __syncthreads();
#pragma unroll
  for (int i = 0; i < 4; ++i)
    out[(size_t)(c0 + ty + i * 8) * R + (r0 + tx)] = (_Float16)tile[tx][ty + i * 8];
}

// ---------------- 128x128 GEMM, BK=64, fragment-major LDS (0-conflict), high occupancy ----
// C[m][n] = sum_k A[m][k]*Bt[n][k] + bias[n].  A:[M][1024], Bt:[N][1024] f16, K=1024.
// 256 threads = 4 waves (2 wm x 2 wn), per-wave 64x64 (acc[4][4]).
// LDS slot s: row=(s>>7)*16+(s&15), col=((s>>6)&1)*32+((s>>4)&3)*8 -> reads are
// base + lane*16, conflict-free by construction (verified 0 conflicts in R4/R5).
// Single buffer, 2 barriers per K-tile (16 tiles), 32 KiB LDS -> 4 blocks/CU.
template <int EPI>
__global__ __launch_bounds__(256, 4) void gemm128_kernel(
    const _Float16* __restrict__ A, const _Float16* __restrict__ Bt,
    const float* __restrict__ bias, _Float16* __restrict__ outQ,
    _Float16* __restrict__ outK, _Float16* __restrict__ outV,
    float* __restrict__ outF, int NB) {
  __shared__ _Float16 Al[8192];  // 128 x 64
  __shared__ _Float16 Bl[8192];

  const int tid = threadIdx.x;
  const int lane = tid & 63;
  const int w = tid >> 6;
  const int wm = w >> 1, wn = w & 1;

  int wg = blockIdx.x;
  const int cpx = gridDim.x >> 3;  // grid % 8 == 0 -> bijective XCD swizzle (T1)
  wg = (wg & 7) * cpx + (wg >> 3);
  const int bm = wg / NB, bn = wg % NB;
  const int m0 = bm * 128;
  const int n0 = bn * 128;

  f32x4 acc[4][4];
#pragma unroll
  for (int m = 0; m < 4; ++m)
#pragma unroll
    for (int n = 0; n < 4; ++n) acc[m][n] = (f32x4){0.f, 0.f, 0.f, 0.f};

#pragma unroll 1
  for (int t = 0; t < 16; ++t) {
    const int k0 = t * 64;
    // stage A+B tiles (fragment-major): 8 gload_lds per thread
#pragma unroll
    for (int it = 0; it < 4; ++it) {
      const int s = it * 256 + tid;
      const int row = ((s >> 7) << 4) + (s & 15);
      const int col = ((s >> 6) & 1) * 32 + ((s >> 4) & 3) * 8;
      gload_lds16(&A[(size_t)(m0 + row) * 1024 + k0 + col], &Al[s * 8]);
      gload_lds16(&Bt[(size_t)(n0 + row) * 1024 + k0 + col], &Bl[s * 8]);
    }
    __syncthreads();  // drains vmcnt -> tiles ready
#pragma unroll
    for (int kk = 0; kk < 2; ++kk) {
      h8_t af[4], bf[4];
#pragma unroll
      for (int mf = 0; mf < 4; ++mf)
        af[mf] = *(const h8_t*)&Al[(((wm * 4 + mf) * 2 + kk) * 64 + lane) * 8];
#pragma unroll
      for (int nf = 0; nf < 4; ++nf)
        bf[nf] = *(const h8_t*)&Bl[(((wn * 4 + nf) * 2 + kk) * 64 + lane) * 8];
#pragma unroll
      for (int mf = 0; mf < 4; ++mf)
#pragma unroll
        for (int nf = 0; nf < 4; ++nf)
          acc[mf][nf] = MFMA_16x16x32_F16(af[mf], bf[nf], acc[mf][nf]);
    }
    __syncthreads();  // all reads done -> safe to overwrite
  }

  // ---- epilogue
#pragma unroll
  for (int mf = 0; mf < 4; ++mf) {
#pragma unroll
    for (int nf = 0; nf < 4; ++nf) {
      const int gn = n0 + wn * 64 + nf * 16 + (lane & 15);
      const int tm0 = m0 + wm * 64 + mf * 16 + (lane >> 4) * 4;
      const float bv = bias[gn];
      if (EPI == 0) {
        const int which = gn >> 10;  // 0=Q 1=K 2=V
        const int nn = gn & 1023;
        const int hh = nn >> 6, d = nn & 63;
        const int t0 = tm0 & 2047, b = tm0 >> 11;
        const int bh = b * 16 + hh;
        if (which == 2) {
          h4_t pack;
#pragma unroll
          for (int r = 0; r < 4; ++r) pack[r] = (_Float16)(acc[mf][nf][r] + bv);
          *reinterpret_cast<h4_t*>(&outV[((size_t)bh * 64 + d) * 2048 + t0]) = pack;
        } else {
          _Float16* dst = (which == 0) ? outQ : outK;
          // Q pre-scaled by log2(e)/sqrt(D) so attention can use exp2 directly
          const float scale = (which == 0) ? 0.18033688011112042f : 1.0f;
#pragma unroll
          for (int r = 0; r < 4; ++r)
            dst[((size_t)bh * 2048 + t0 + r) * 64 + d] = (_Float16)((acc[mf][nf][r] + bv) * scale);
        }
      } else {
#pragma unroll
        for (int r = 0; r < 4; ++r)
          outF[(size_t)(tm0 + r) * 1024 + gn] = acc[mf][nf][r] + bv;
      }
    }
  }
}

// ---------------- flash attention (causal), swapped-QK in-register softmax ----------------
__device__ inline void stage_kv(const _Float16* __restrict__ Kbh, const _Float16* __restrict__ Vbh,
                                int kt, _Float16* Kd, _Float16* Vd, int w, int lane) {
  const _Float16* Kg = Kbh + (size_t)kt * 64 * 64;
  const _Float16* Vg = Vbh + kt * 64;
#pragma unroll
  for (int c = 0; c < 2; ++c) {
    const int idx = (2 * w + c) * 64 + lane;
    const int row = idx >> 3;
    const int chs = (idx & 7) ^ (row & 7);  // pre-swizzled global source (T2 via m173)
    gload_lds16(Kg + row * 64 + chs * 8, Kd + idx * 8);
    gload_lds16(Vg + (size_t)row * 2048 + chs * 8, Vd + idx * 8);
  }
}

// pack 16 exp'd f32 into 2 PV B-fragments
__device__ inline void pack_pfrag(const float* e, h8_t* out) {
  unsigned u[8];
#pragma unroll
  for (int i = 0; i < 8; ++i) {
    auto hv = __builtin_amdgcn_cvt_pkrtz(e[2 * i], e[2 * i + 1]);
    u[i] = __builtin_bit_cast(unsigned, hv);
  }
  auto r02 = __builtin_amdgcn_permlane32_swap(u[0], u[2], false, false);
  auto r13 = __builtin_amdgcn_permlane32_swap(u[1], u[3], false, false);
  auto r46 = __builtin_amdgcn_permlane32_swap(u[4], u[6], false, false);
  auto r57 = __builtin_amdgcn_permlane32_swap(u[5], u[7], false, false);
  u32x4 w0 = {(unsigned)r02[0], (unsigned)r13[0], (unsigned)r02[1], (unsigned)r13[1]};
  u32x4 w1 = {(unsigned)r46[0], (unsigned)r57[0], (unsigned)r46[1], (unsigned)r57[1]};
  out[0] = __builtin_bit_cast(h8_t, w0);
  out[1] = __builtin_bit_cast(h8_t, w1);
}

__global__ __launch_bounds__(256, 2) void attn_kernel(
    const _Float16* __restrict__ Q, const _Float16* __restrict__ K,
    const _Float16* __restrict__ Vt, _Float16* __restrict__ O) {
  __shared__ _Float16 Kl[2][64 * 64];
  __shared__ _Float16 Vl[2][64 * 64];
  const int tid = threadIdx.x;
  const int lane = tid & 63;
  const int w = tid >> 6;
  const int hi = lane >> 5;
  const int l31 = lane & 31;
  const int bh = blockIdx.x >> 3;
  const int pr = blockIdx.x & 7;
  const int b = bh >> 4, h = bh & 15;
  const _Float16* Kbh = K + (size_t)bh * 2048 * 64;
  const _Float16* Vbh = Vt + (size_t)bh * 64 * 2048;

#pragma unroll
  for (int gi = 0; gi < 2; ++gi) {
    const int g = gi ? (15 - pr) : pr;
    const int nt = 2 * g + 2;
    const int qbase = g * 128 + w * 32;
    const int qrow = qbase + l31;

    h8_t qf[4];
    const _Float16* Qp = Q + ((size_t)bh * 2048 + qrow) * 64 + hi * 8;
#pragma unroll
    for (int ds = 0; ds < 4; ++ds)
      qf[ds] = *reinterpret_cast<const h8_t*>(Qp + ds * 16);

    f32x16 oa[2] = {};
    float m = -1e30f, lsum = 0.f;

    stage_kv(Kbh, Vbh, 0, &Kl[0][0], &Vl[0][0], w, lane);
    __syncthreads();

    for (int kt = 0; kt < nt; ++kt) {
      const int cur = kt & 1;
      if (kt + 1 < nt)
        stage_kv(Kbh, Vbh, kt + 1, &Kl[cur ^ 1][0], &Vl[cur ^ 1][0], w, lane);

      if (kt * 64 <= qbase + 31) {
        const char* Kb = (const char*)&Kl[cur][0];
        const char* Vb = (const char*)&Vl[cur][0];
        f32x16 s0 = {}, s1 = {};
#pragma unroll
        for (int ds = 0; ds < 4; ++ds) {
          const int bc = ds * 32 + hi * 16;
          h8_t kf0 = *(const h8_t*)(Kb + l31 * 128 + (bc ^ ((l31 & 7) << 4)));
          h8_t kf1 = *(const h8_t*)(Kb + (32 + l31) * 128 + (bc ^ ((l31 & 7) << 4)));
          s0 = MFMA_32x32x16_F16(kf0, qf[ds], s0);
          s1 = MFMA_32x32x16_F16(kf1, qf[ds], s1);
        }
        if (kt >= 2 * g) {
#pragma unroll
          for (int r = 0; r < 16; ++r) {
            const int kr = kt * 64 + (r & 3) + 8 * (r >> 2) + 4 * hi;
            if (kr > qrow) s0[r] = -1e30f;
            if (kr + 32 > qrow) s1[r] = -1e30f;
          }
        }
        float t[16];
#pragma unroll
        for (int r = 0; r < 16; ++r) t[r] = fmaxf(s0[r], s1[r]);
#pragma unroll
        for (int st = 8; st >= 1; st >>= 1)
#pragma unroll
          for (int r = 0; r < st; ++r) t[r] = fmaxf(t[r], t[r + st]);
        const float pmax = fmaxf(t[0], __shfl_xor(t[0], 32));
        const float mnew = fmaxf(m, pmax);
        if (__any(mnew > m + 8.f)) {
          const float al = __builtin_amdgcn_exp2f(m - mnew);
          lsum *= al;
#pragma unroll
          for (int r = 0; r < 16; ++r) { oa[0][r] *= al; oa[1][r] *= al; }
          m = mnew;
        }
        float e0[16], e1[16];
#pragma unroll
        for (int r = 0; r < 16; ++r) {
          e0[r] = __builtin_amdgcn_exp2f(s0[r] - m);
          e1[r] = __builtin_amdgcn_exp2f(s1[r] - m);
        }
        float ps = 0.f;
#pragma unroll
        for (int r = 0; r < 16; ++r) ps += e0[r] + e1[r];
        ps += __shfl_xor(ps, 32);
        lsum += ps;
        h8_t pf[4];
        pack_pfrag(e0, pf + 0);
        pack_pfrag(e1, pf + 2);
#pragma unroll
        for (int dt = 0; dt < 2; ++dt) {
#pragma unroll
          for (int kg = 0; kg < 4; ++kg) {
            const int row = dt * 32 + l31;
            const int bc = kg * 32 + hi * 16;
            h8_t vf = *(const h8_t*)(Vb + row * 128 + (bc ^ ((row & 7) << 4)));
            oa[dt] = MFMA_32x32x16_F16(vf, pf[kg], oa[dt]);
          }
        }
      }
      __syncthreads();
    }

    const float inv = __builtin_amdgcn_rcpf(lsum);
    _Float16* Op = O + ((size_t)b * 2048 + qrow) * 1024 + h * 64;
#pragma unroll
    for (int dt = 0; dt < 2; ++dt) {
#pragma unroll
      for (int rg = 0; rg < 4; ++rg) {
        h4_t pk4;
#pragma unroll
        for (int i = 0; i < 4; ++i) pk4[i] = (_Float16)(oa[dt][rg * 4 + i] * inv);
        *reinterpret_cast<h4_t*>(Op + dt * 32 + rg * 8 + hi * 4) = pk4;
      }
    }
  }
}

extern "C" void kernel_launch(void* const* d_in, const int* in_sizes, int n_in,
                              void* d_out, int out_size, void* d_ws, size_t ws_size,
                              hipStream_t stream) {
  (void)in_sizes; (void)n_in; (void)out_size; (void)ws_size;
  const float* x = (const float*)d_in[0];
  const float* w_qkv = (const float*)d_in[1];
  const float* b_qkv = (const float*)d_in[2];
  const float* w_out = (const float*)d_in[3];
  const float* b_out = (const float*)d_in[4];
  float* out = (float*)d_out;

  char* ws = (char*)d_ws;
  size_t off = 0;
  auto alloc = [&](size_t bytes) {
    void* p = ws + off;
    off += (bytes + 255) & ~(size_t)255;
    return p;
  };
  _Float16* x16 = (_Float16*)alloc((size_t)8192 * 1024 * 2);
  _Float16* wqkvT = (_Float16*)alloc((size_t)3072 * 1024 * 2);
  _Float16* woutT = (_Float16*)alloc((size_t)1024 * 1024 * 2);
  _Float16* Qh = (_Float16*)alloc((size_t)64 * 2048 * 64 * 2);
  _Float16* Kh = (_Float16*)alloc((size_t)64 * 2048 * 64 * 2);
  _Float16* Vth = (_Float16*)alloc((size_t)64 * 64 * 2048 * 2);
  _Float16* Oh = (_Float16*)alloc((size_t)8192 * 1024 * 2);

  cvt_f16_kernel<<<8192, 256, 0, stream>>>(x, x16, 8192 * 1024 / 4);
  transpose_cvt_kernel<<<dim3(3072 / 32, 1024 / 32), 256, 0, stream>>>(w_qkv, wqkvT, 1024, 3072);
  transpose_cvt_kernel<<<dim3(1024 / 32, 1024 / 32), 256, 0, stream>>>(w_out, woutT, 1024, 1024);
  gemm128_kernel<0><<<64 * 24, 256, 0, stream>>>(x16, wqkvT, b_qkv, Qh, Kh, Vth, nullptr, 24);
  attn_kernel<<<64 * 8, 256, 0, stream>>>(Qh, Kh, Vth, Oh);
  gemm128_kernel<1><<<64 * 8, 256, 0, stream>>>(Oh, woutT, b_out, nullptr, nullptr, nullptr, out, 8);
}

// Round 7
// 185.726 us; speedup vs baseline: 1.1613x; 1.1613x over previous
//
#include <hip/hip_runtime.h>
#include <cstdint>
#include <cstddef>

typedef _Float16 h8_t __attribute__((ext_vector_type(8)));
typedef _Float16 h4_t __attribute__((ext_vector_type(4)));
typedef float f32x4 __attribute__((ext_vector_type(4)));
typedef float f32x16 __attribute__((ext_vector_type(16)));
typedef unsigned u32x4 __attribute__((ext_vector_type(4)));

#define MFMA_16x16x32_F16(a, b, c) __builtin_amdgcn_mfma_f32_16x16x32_f16(a, b, c, 0, 0, 0)
#define MFMA_32x32x16_F16(a, b, c) __builtin_amdgcn_mfma_f32_32x32x16_f16(a, b, c, 0, 0, 0)

__device__ inline void gload_lds16(const void* g, void* l) {
  __builtin_amdgcn_global_load_lds((const __attribute__((address_space(1))) void*)g,
                                   (__attribute__((address_space(3))) void*)l, 16, 0, 0);
}

// ---------------- convert f32 -> f16 ----------------
__global__ void cvt_f16_kernel(const float* __restrict__ in, _Float16* __restrict__ out, int n4) {
  int i = blockIdx.x * 256 + threadIdx.x;
  if (i >= n4) return;
  float4 v = reinterpret_cast<const float4*>(in)[i];
  h4_t h;
  h[0] = (_Float16)v.x; h[1] = (_Float16)v.y; h[2] = (_Float16)v.z; h[3] = (_Float16)v.w;
  reinterpret_cast<h4_t*>(out)[i] = h;
}

// ---------------- transpose + convert: in[R][Cc] f32 -> out[Cc][R] f16 ----------------
__global__ void transpose_cvt_kernel(const float* __restrict__ in, _Float16* __restrict__ out,
                                     int R, int Cc) {
  __shared__ float tile[32][33];
  int tx = threadIdx.x & 31;
  int ty = threadIdx.x >> 5;
  int c0 = blockIdx.x * 32;
  int r0 = blockIdx.y * 32;
#pragma unroll
  for (int i = 0; i < 4; ++i)
    tile[ty + i * 8][tx] = in[(size_t)(r0 + ty + i * 8) * Cc + (c0 + tx)];
  __syncthreads();
#pragma unroll
  for (int i = 0; i < 4; ++i)
    out[(size_t)(c0 + ty + i * 8) * R + (r0 + tx)] = (_Float16)tile[tx][ty + i * 8];
}

// ---------------- GEMM  C[m][n] = sum_k A[m][k]*Bt[n][k] + bias[n] ----------------
// R3 skeleton (78us proven): 128x128 tile, BK=32, 4 waves (2x2), 64x64/wave, natural
// block order (NO XCD swizzle -- R6 showed it hurts B-panel L2 residency here).
// Grafts: (a) T3-min 2-phase: LDS double-buffer, stage(t+1) issued BEFORE compute(t),
// one __syncthreads per K-tile (drains vmcnt; no manual waitcnt -> no race surface).
// (b) bank-conflict XOR: LDS [row][32] chunk ^= (row>>1)&3 on BOTH the pre-swizzled
// global_load_lds source and the ds_read address (involution, rule #21) -> 2-way (free).
template <int EPI>
__global__ __launch_bounds__(256, 2) void gemm_bt_kernel(
    const _Float16* __restrict__ A, const _Float16* __restrict__ Bt,
    const float* __restrict__ bias, _Float16* __restrict__ outQ,
    _Float16* __restrict__ outK, _Float16* __restrict__ outV,
    float* __restrict__ outF, int NB) {
  __shared__ _Float16 Al[2][4096];
  __shared__ _Float16 Bl[2][4096];
  const int tid = threadIdx.x;
  const int lane = tid & 63;
  const int w = tid >> 6;
  const int bm = blockIdx.x / NB;
  const int bn = blockIdx.x % NB;
  const int wm = w & 1, wn = w >> 1;
  const int m0 = bm * 128, n0 = bn * 128;

  f32x4 acc[4][4];
#pragma unroll
  for (int m = 0; m < 4; ++m)
#pragma unroll
    for (int n = 0; n < 4; ++n) acc[m][n] = (f32x4){0.f, 0.f, 0.f, 0.f};

  // stage K-tile kt into buf: seg=w*2+c covers rows seg*16..+15; LDS dest linear
  // byte seg*1024+lane*16 == (row, chunk=lane&3); source chunk pre-XORed.
  auto stage = [&](int buf, int kt) {
    const int k0 = kt * 32;
#pragma unroll
    for (int c = 0; c < 2; ++c) {
      const int seg = w * 2 + c;
      const int row = seg * 16 + (lane >> 2);
      const int chunk = (lane & 3) ^ ((row >> 1) & 3);
      gload_lds16(&A[(size_t)(m0 + row) * 1024 + k0 + chunk * 8], &Al[buf][seg * 512 + lane * 8]);
      gload_lds16(&Bt[(size_t)(n0 + row) * 1024 + k0 + chunk * 8], &Bl[buf][seg * 512 + lane * 8]);
    }
  };

  stage(0, 0);
  __syncthreads();

#pragma unroll 1
  for (int t = 0; t < 32; ++t) {
    const int buf = t & 1;
    if (t + 1 < 32) stage(buf ^ 1, t + 1);  // issue-early: latency hides under compute
    h8_t af[4], bf[4];
#pragma unroll
    for (int i = 0; i < 4; ++i) {
      const int row = wm * 64 + i * 16 + (lane & 15);
      af[i] = *(const h8_t*)&Al[buf][row * 32 + (((lane >> 4) ^ ((row >> 1) & 3)) * 8)];
    }
#pragma unroll
    for (int j = 0; j < 4; ++j) {
      const int row = wn * 64 + j * 16 + (lane & 15);
      bf[j] = *(const h8_t*)&Bl[buf][row * 32 + (((lane >> 4) ^ ((row >> 1) & 3)) * 8)];
    }
#pragma unroll
    for (int i = 0; i < 4; ++i)
#pragma unroll
      for (int j = 0; j < 4; ++j)
        acc[i][j] = MFMA_16x16x32_F16(af[i], bf[j], acc[i][j]);
    __syncthreads();  // drains this iter's stage (vmcnt 0) + guards buf swap
  }

  const int gm0 = bm * 128 + wm * 64;
  const int gn0 = bn * 128 + wn * 64;
#pragma unroll
  for (int i = 0; i < 4; ++i) {
#pragma unroll
    for (int j = 0; j < 4; ++j) {
      const int gn = gn0 + j * 16 + (lane & 15);
      const int tm0 = gm0 + i * 16 + (lane >> 4) * 4;
      const float bv = bias[gn];
      if (EPI == 0) {
        const int which = gn >> 10;  // 0=Q 1=K 2=V
        const int nn = gn & 1023;
        const int h = nn >> 6, d = nn & 63;
        const int t0 = tm0 & 2047, b = tm0 >> 11;
        const int bh = b * 16 + h;
        if (which == 2) {
          h4_t pack;
#pragma unroll
          for (int r = 0; r < 4; ++r) pack[r] = (_Float16)(acc[i][j][r] + bv);
          *reinterpret_cast<h4_t*>(&outV[((size_t)bh * 64 + d) * 2048 + t0]) = pack;
        } else {
          _Float16* dst = (which == 0) ? outQ : outK;
          // Q pre-scaled by log2(e)/sqrt(D) so attention can use exp2 directly
          const float scale = (which == 0) ? 0.18033688011112042f : 1.0f;
#pragma unroll
          for (int r = 0; r < 4; ++r)
            dst[((size_t)bh * 2048 + t0 + r) * 64 + d] = (_Float16)((acc[i][j][r] + bv) * scale);
        }
      } else {
#pragma unroll
        for (int r = 0; r < 4; ++r)
          outF[(size_t)(tm0 + r) * 1024 + gn] = acc[i][j][r] + bv;
      }
    }
  }
}

// ---------------- flash attention (causal), swapped-QK in-register softmax ----------------
__device__ inline void stage_kv(const _Float16* __restrict__ Kbh, const _Float16* __restrict__ Vbh,
                                int kt, _Float16* Kd, _Float16* Vd, int w, int lane) {
  const _Float16* Kg = Kbh + (size_t)kt * 64 * 64;
  const _Float16* Vg = Vbh + kt * 64;
#pragma unroll
  for (int c = 0; c < 2; ++c) {
    const int idx = (2 * w + c) * 64 + lane;
    const int row = idx >> 3;
    const int chs = (idx & 7) ^ (row & 7);  // pre-swizzled global source (T2 via m173)
    gload_lds16(Kg + row * 64 + chs * 8, Kd + idx * 8);
    gload_lds16(Vg + (size_t)row * 2048 + chs * 8, Vd + idx * 8);
  }
}

// pack 16 exp'd f32 into 2 PV B-fragments
__device__ inline void pack_pfrag(const float* e, h8_t* out) {
  unsigned u[8];
#pragma unroll
  for (int i = 0; i < 8; ++i) {
    auto hv = __builtin_amdgcn_cvt_pkrtz(e[2 * i], e[2 * i + 1]);
    u[i] = __builtin_bit_cast(unsigned, hv);
  }
  auto r02 = __builtin_amdgcn_permlane32_swap(u[0], u[2], false, false);
  auto r13 = __builtin_amdgcn_permlane32_swap(u[1], u[3], false, false);
  auto r46 = __builtin_amdgcn_permlane32_swap(u[4], u[6], false, false);
  auto r57 = __builtin_amdgcn_permlane32_swap(u[5], u[7], false, false);
  u32x4 w0 = {(unsigned)r02[0], (unsigned)r13[0], (unsigned)r02[1], (unsigned)r13[1]};
  u32x4 w1 = {(unsigned)r46[0], (unsigned)r57[0], (unsigned)r46[1], (unsigned)r57[1]};
  out[0] = __builtin_bit_cast(h8_t, w0);
  out[1] = __builtin_bit_cast(h8_t, w1);
}

__global__ __launch_bounds__(256, 2) void attn_kernel(
    const _Float16* __restrict__ Q, const _Float16* __restrict__ K,
    const _Float16* __restrict__ Vt, _Float16* __restrict__ O) {
  __shared__ _Float16 Kl[2][64 * 64];
  __shared__ _Float16 Vl[2][64 * 64];
  const int tid = threadIdx.x;
  const int lane = tid & 63;
  const int w = tid >> 6;
  const int hi = lane >> 5;
  const int l31 = lane & 31;
  const int bh = blockIdx.x >> 3;
  const int pr = blockIdx.x & 7;
  const int b = bh >> 4, h = bh & 15;
  const _Float16* Kbh = K + (size_t)bh * 2048 * 64;
  const _Float16* Vbh = Vt + (size_t)bh * 64 * 2048;

#pragma unroll
  for (int gi = 0; gi < 2; ++gi) {
    const int g = gi ? (15 - pr) : pr;
    const int nt = 2 * g + 2;
    const int qbase = g * 128 + w * 32;
    const int qrow = qbase + l31;

    h8_t qf[4];
    const _Float16* Qp = Q + ((size_t)bh * 2048 + qrow) * 64 + hi * 8;
#pragma unroll
    for (int ds = 0; ds < 4; ++ds)
      qf[ds] = *reinterpret_cast<const h8_t*>(Qp + ds * 16);

    f32x16 oa[2] = {};
    float m = -1e30f, lsum = 0.f;

    stage_kv(Kbh, Vbh, 0, &Kl[0][0], &Vl[0][0], w, lane);
    __syncthreads();

    for (int kt = 0; kt < nt; ++kt) {
      const int cur = kt & 1;
      if (kt + 1 < nt)
        stage_kv(Kbh, Vbh, kt + 1, &Kl[cur ^ 1][0], &Vl[cur ^ 1][0], w, lane);

      if (kt * 64 <= qbase + 31) {
        const char* Kb = (const char*)&Kl[cur][0];
        const char* Vb = (const char*)&Vl[cur][0];
        f32x16 s0 = {}, s1 = {};
#pragma unroll
        for (int ds = 0; ds < 4; ++ds) {
          const int bc = ds * 32 + hi * 16;
          h8_t kf0 = *(const h8_t*)(Kb + l31 * 128 + (bc ^ ((l31 & 7) << 4)));
          h8_t kf1 = *(const h8_t*)(Kb + (32 + l31) * 128 + (bc ^ ((l31 & 7) << 4)));
          s0 = MFMA_32x32x16_F16(kf0, qf[ds], s0);
          s1 = MFMA_32x32x16_F16(kf1, qf[ds], s1);
        }
        if (kt >= 2 * g) {
#pragma unroll
          for (int r = 0; r < 16; ++r) {
            const int kr = kt * 64 + (r & 3) + 8 * (r >> 2) + 4 * hi;
            if (kr > qrow) s0[r] = -1e30f;
            if (kr + 32 > qrow) s1[r] = -1e30f;
          }
        }
        float t[16];
#pragma unroll
        for (int r = 0; r < 16; ++r) t[r] = fmaxf(s0[r], s1[r]);
#pragma unroll
        for (int st = 8; st >= 1; st >>= 1)
#pragma unroll
          for (int r = 0; r < st; ++r) t[r] = fmaxf(t[r], t[r + st]);
        const float pmax = fmaxf(t[0], __shfl_xor(t[0], 32));
        const float mnew = fmaxf(m, pmax);
        if (__any(mnew > m + 8.f)) {
          const float al = __builtin_amdgcn_exp2f(m - mnew);
          lsum *= al;
#pragma unroll
          for (int r = 0; r < 16; ++r) { oa[0][r] *= al; oa[1][r] *= al; }
          m = mnew;
        }
        float e0[16], e1[16];
#pragma unroll
        for (int r = 0; r < 16; ++r) {
          e0[r] = __builtin_amdgcn_exp2f(s0[r] - m);
          e1[r] = __builtin_amdgcn_exp2f(s1[r] - m);
        }
        float ps = 0.f;
#pragma unroll
        for (int r = 0; r < 16; ++r) ps += e0[r] + e1[r];
        ps += __shfl_xor(ps, 32);
        lsum += ps;
        h8_t pf[4];
        pack_pfrag(e0, pf + 0);
        pack_pfrag(e1, pf + 2);
#pragma unroll
        for (int dt = 0; dt < 2; ++dt) {
#pragma unroll
          for (int kg = 0; kg < 4; ++kg) {
            const int row = dt * 32 + l31;
            const int bc = kg * 32 + hi * 16;
            h8_t vf = *(const h8_t*)(Vb + row * 128 + (bc ^ ((row & 7) << 4)));
            oa[dt] = MFMA_32x32x16_F16(vf, pf[kg], oa[dt]);
          }
        }
      }
      __syncthreads();
    }

    const float inv = __builtin_amdgcn_rcpf(lsum);
    _Float16* Op = O + ((size_t)b * 2048 + qrow) * 1024 + h * 64;
#pragma unroll
    for (int dt = 0; dt < 2; ++dt) {
#pragma unroll
      for (int rg = 0; rg < 4; ++rg) {
        h4_t pk4;
#pragma unroll
        for (int i = 0; i < 4; ++i) pk4[i] = (_Float16)(oa[dt][rg * 4 + i] * inv);
        *reinterpret_cast<h4_t*>(Op + dt * 32 + rg * 8 + hi * 4) = pk4;
      }
    }
  }
}

extern "C" void kernel_launch(void* const* d_in, const int* in_sizes, int n_in,
                              void* d_out, int out_size, void* d_ws, size_t ws_size,
                              hipStream_t stream) {
  (void)in_sizes; (void)n_in; (void)out_size; (void)ws_size;
  const float* x = (const float*)d_in[0];
  const float* w_qkv = (const float*)d_in[1];
  const float* b_qkv = (const float*)d_in[2];
  const float* w_out = (const float*)d_in[3];
  const float* b_out = (const float*)d_in[4];
  float* out = (float*)d_out;

  char* ws = (char*)d_ws;
  size_t off = 0;
  auto alloc = [&](size_t bytes) {
    void* p = ws + off;
    off += (bytes + 255) & ~(size_t)255;
    return p;
  };
  _Float16* x16 = (_Float16*)alloc((size_t)8192 * 1024 * 2);
  _Float16* wqkvT = (_Float16*)alloc((size_t)3072 * 1024 * 2);
  _Float16* woutT = (_Float16*)alloc((size_t)1024 * 1024 * 2);
  _Float16* Qh = (_Float16*)alloc((size_t)64 * 2048 * 64 * 2);
  _Float16* Kh = (_Float16*)alloc((size_t)64 * 2048 * 64 * 2);
  _Float16* Vth = (_Float16*)alloc((size_t)64 * 64 * 2048 * 2);
  _Float16* Oh = (_Float16*)alloc((size_t)8192 * 1024 * 2);

  cvt_f16_kernel<<<8192, 256, 0, stream>>>(x, x16, 8192 * 1024 / 4);
  transpose_cvt_kernel<<<dim3(3072 / 32, 1024 / 32), 256, 0, stream>>>(w_qkv, wqkvT, 1024, 3072);
  transpose_cvt_kernel<<<dim3(1024 / 32, 1024 / 32), 256, 0, stream>>>(w_out, woutT, 1024, 1024);
  gemm_bt_kernel<0><<<64 * 24, 256, 0, stream>>>(x16, wqkvT, b_qkv, Qh, Kh, Vth, nullptr, 24);
  attn_kernel<<<64 * 8, 256, 0, stream>>>(Qh, Kh, Vth, Oh);
  gemm_bt_kernel<1><<<64 * 8, 256, 0, stream>>>(Oh, woutT, b_out, nullptr, nullptr, nullptr, out, 8);
}

// Round 8
// 184.194 us; speedup vs baseline: 1.1709x; 1.0083x over previous
//
#include <hip/hip_runtime.h>
#include <cstdint>
#include <cstddef>

typedef _Float16 h8_t __attribute__((ext_vector_type(8)));
typedef _Float16 h4_t __attribute__((ext_vector_type(4)));
typedef float f32x4 __attribute__((ext_vector_type(4)));
typedef float f32x16 __attribute__((ext_vector_type(16)));
typedef unsigned u32x4 __attribute__((ext_vector_type(4)));

#define MFMA_16x16x32_F16(a, b, c) __builtin_amdgcn_mfma_f32_16x16x32_f16(a, b, c, 0, 0, 0)
#define MFMA_32x32x16_F16(a, b, c) __builtin_amdgcn_mfma_f32_32x32x16_f16(a, b, c, 0, 0, 0)

__device__ inline void gload_lds16(const void* g, void* l) {
  __builtin_amdgcn_global_load_lds((const __attribute__((address_space(1))) void*)g,
                                   (__attribute__((address_space(3))) void*)l, 16, 0, 0);
}

#define CFENCE asm volatile("" ::: "memory")
#define RAW_BAR() do { CFENCE; __builtin_amdgcn_s_barrier(); CFENCE; } while (0)

// ---------------- convert f32 -> f16 ----------------
__global__ void cvt_f16_kernel(const float* __restrict__ in, _Float16* __restrict__ out, int n4) {
  int i = blockIdx.x * 256 + threadIdx.x;
  if (i >= n4) return;
  float4 v = reinterpret_cast<const float4*>(in)[i];
  h4_t h;
  h[0] = (_Float16)v.x; h[1] = (_Float16)v.y; h[2] = (_Float16)v.z; h[3] = (_Float16)v.w;
  reinterpret_cast<h4_t*>(out)[i] = h;
}

// ---------------- transpose + convert: in[R][Cc] f32 -> out[Cc][R] f16 ----------------
__global__ void transpose_cvt_kernel(const float* __restrict__ in, _Float16* __restrict__ out,
                                     int R, int Cc) {
  __shared__ float tile[32][33];
  int tx = threadIdx.x & 31;
  int ty = threadIdx.x >> 5;
  int c0 = blockIdx.x * 32;
  int r0 = blockIdx.y * 32;
#pragma unroll
  for (int i = 0; i < 4; ++i)
    tile[ty + i * 8][tx] = in[(size_t)(r0 + ty + i * 8) * Cc + (c0 + tx)];
  __syncthreads();
#pragma unroll
  for (int i = 0; i < 4; ++i)
    out[(size_t)(c0 + ty + i * 8) * R + (r0 + tx)] = (_Float16)tile[tx][ty + i * 8];
}

// ---------------- GEMM  C[m][n] = sum_k A[m][k]*Bt[n][k] + bias[n] ----------------
// R7 skeleton + T4 counted-vmcnt: TRIPLE-buffered BK=32 (48 KiB -> 3 blocks/CU),
// stage(t+2) issued at iter top, end-of-iter wait = s_waitcnt vmcnt(4) (stage t+1
// done; t+2 stays in flight) + raw s_barrier -- never vmcnt(0) mid-loop.
// Safety: reads of buf b complete before same-iter barrier (MFMA data-dep);
// next write to b issued only after that barrier; vmcnt(4)+barrier => t+1's DMA
// visible to all waves before any read. Uniform control flow (no divergent bars).
// Bank-conflict XOR (chunk ^= (row>>1)&3) on both sides, proven 0 conflicts.
template <int EPI>
__global__ __launch_bounds__(256, 3) void gemm_bt_kernel(
    const _Float16* __restrict__ A, const _Float16* __restrict__ Bt,
    const float* __restrict__ bias, _Float16* __restrict__ outQ,
    _Float16* __restrict__ outK, _Float16* __restrict__ outV,
    float* __restrict__ outF, int NB) {
  __shared__ _Float16 Al[3][4096];
  __shared__ _Float16 Bl[3][4096];
  const int tid = threadIdx.x;
  const int lane = tid & 63;
  const int w = tid >> 6;
  const int bm = blockIdx.x / NB;
  const int bn = blockIdx.x % NB;
  const int wm = w & 1, wn = w >> 1;
  const int m0 = bm * 128, n0 = bn * 128;

  f32x4 acc[4][4];
#pragma unroll
  for (int m = 0; m < 4; ++m)
#pragma unroll
    for (int n = 0; n < 4; ++n) acc[m][n] = (f32x4){0.f, 0.f, 0.f, 0.f};

  // loop-invariant staging sources (k0 added per iter) and linear LDS dests
  const int seg0 = w * 2, seg1 = w * 2 + 1;
  const int r0s = seg0 * 16 + (lane >> 2);
  const int r1s = seg1 * 16 + (lane >> 2);
  const int c0s = ((lane & 3) ^ ((r0s >> 1) & 3)) * 8;
  const int c1s = ((lane & 3) ^ ((r1s >> 1) & 3)) * 8;
  const _Float16* aS0 = A + (size_t)(m0 + r0s) * 1024 + c0s;
  const _Float16* aS1 = A + (size_t)(m0 + r1s) * 1024 + c1s;
  const _Float16* bS0 = Bt + (size_t)(n0 + r0s) * 1024 + c0s;
  const _Float16* bS1 = Bt + (size_t)(n0 + r1s) * 1024 + c1s;
  const int d0 = seg0 * 512 + lane * 8;
  const int d1 = seg1 * 512 + lane * 8;

  auto stage = [&](int buf, int kt) {
    const int k0 = kt * 32;
    gload_lds16(aS0 + k0, &Al[buf][d0]);
    gload_lds16(bS0 + k0, &Bl[buf][d0]);
    gload_lds16(aS1 + k0, &Al[buf][d1]);
    gload_lds16(bS1 + k0, &Bl[buf][d1]);
  };

  // loop-invariant fragment read offsets (XOR folded in; rows fixed per thread)
  int offA[4], offB[4];
#pragma unroll
  for (int i = 0; i < 4; ++i) {
    const int rowA = wm * 64 + i * 16 + (lane & 15);
    offA[i] = rowA * 32 + (((lane >> 4) ^ ((rowA >> 1) & 3)) * 8);
    const int rowB = wn * 64 + i * 16 + (lane & 15);
    offB[i] = rowB * 32 + (((lane >> 4) ^ ((rowB >> 1) & 3)) * 8);
  }

  // prologue: stage K-tiles 0,1 (8 in flight); wait tile 0 (4 remain)
  stage(0, 0);
  stage(1, 1);
  asm volatile("s_waitcnt vmcnt(4)" ::: "memory");
  RAW_BAR();

  int cur = 0;
#pragma unroll 1
  for (int t = 0; t < 32; ++t) {
    int nb = cur + 2; if (nb >= 3) nb -= 3;
    if (t + 2 < 32) stage(nb, t + 2);  // issue-early into the retired buffer
    const _Float16* Ab = &Al[cur][0];
    const _Float16* Bb = &Bl[cur][0];
    h8_t af[4], bf[4];
#pragma unroll
    for (int i = 0; i < 4; ++i) af[i] = *(const h8_t*)&Ab[offA[i]];
#pragma unroll
    for (int j = 0; j < 4; ++j) bf[j] = *(const h8_t*)&Bb[offB[j]];
#pragma unroll
    for (int i = 0; i < 4; ++i)
#pragma unroll
      for (int j = 0; j < 4; ++j)
        acc[i][j] = MFMA_16x16x32_F16(af[i], bf[j], acc[i][j]);
    if (t < 31) {
      if (t + 2 < 32) asm volatile("s_waitcnt vmcnt(4)" ::: "memory");
      else asm volatile("s_waitcnt vmcnt(0)" ::: "memory");
      RAW_BAR();
    }
    ++cur; if (cur == 3) cur = 0;
  }

  const int gm0 = bm * 128 + wm * 64;
  const int gn0 = bn * 128 + wn * 64;
#pragma unroll
  for (int i = 0; i < 4; ++i) {
#pragma unroll
    for (int j = 0; j < 4; ++j) {
      const int gn = gn0 + j * 16 + (lane & 15);
      const int tm0 = gm0 + i * 16 + (lane >> 4) * 4;
      const float bv = bias[gn];
      if (EPI == 0) {
        const int which = gn >> 10;  // 0=Q 1=K 2=V
        const int nn = gn & 1023;
        const int h = nn >> 6, d = nn & 63;
        const int t0 = tm0 & 2047, b = tm0 >> 11;
        const int bh = b * 16 + h;
        if (which == 2) {
          h4_t pack;
#pragma unroll
          for (int r = 0; r < 4; ++r) pack[r] = (_Float16)(acc[i][j][r] + bv);
          *reinterpret_cast<h4_t*>(&outV[((size_t)bh * 64 + d) * 2048 + t0]) = pack;
        } else {
          _Float16* dst = (which == 0) ? outQ : outK;
          // Q pre-scaled by log2(e)/sqrt(D) so attention can use exp2 directly
          const float scale = (which == 0) ? 0.18033688011112042f : 1.0f;
#pragma unroll
          for (int r = 0; r < 4; ++r)
            dst[((size_t)bh * 2048 + t0 + r) * 64 + d] = (_Float16)((acc[i][j][r] + bv) * scale);
        }
      } else {
#pragma unroll
        for (int r = 0; r < 4; ++r)
          outF[(size_t)(tm0 + r) * 1024 + gn] = acc[i][j][r] + bv;
      }
    }
  }
}

// ---------------- flash attention (causal), swapped-QK in-register softmax ----------------
__device__ inline void stage_kv(const _Float16* __restrict__ Kbh, const _Float16* __restrict__ Vbh,
                                int kt, _Float16* Kd, _Float16* Vd, int w, int lane) {
  const _Float16* Kg = Kbh + (size_t)kt * 64 * 64;
  const _Float16* Vg = Vbh + kt * 64;
#pragma unroll
  for (int c = 0; c < 2; ++c) {
    const int idx = (2 * w + c) * 64 + lane;
    const int row = idx >> 3;
    const int chs = (idx & 7) ^ (row & 7);  // pre-swizzled global source (T2 via m173)
    gload_lds16(Kg + row * 64 + chs * 8, Kd + idx * 8);
    gload_lds16(Vg + (size_t)row * 2048 + chs * 8, Vd + idx * 8);
  }
}

// pack 16 exp'd f32 into 2 PV B-fragments
__device__ inline void pack_pfrag(const float* e, h8_t* out) {
  unsigned u[8];
#pragma unroll
  for (int i = 0; i < 8; ++i) {
    auto hv = __builtin_amdgcn_cvt_pkrtz(e[2 * i], e[2 * i + 1]);
    u[i] = __builtin_bit_cast(unsigned, hv);
  }
  auto r02 = __builtin_amdgcn_permlane32_swap(u[0], u[2], false, false);
  auto r13 = __builtin_amdgcn_permlane32_swap(u[1], u[3], false, false);
  auto r46 = __builtin_amdgcn_permlane32_swap(u[4], u[6], false, false);
  auto r57 = __builtin_amdgcn_permlane32_swap(u[5], u[7], false, false);
  u32x4 w0 = {(unsigned)r02[0], (unsigned)r13[0], (unsigned)r02[1], (unsigned)r13[1]};
  u32x4 w1 = {(unsigned)r46[0], (unsigned)r57[0], (unsigned)r46[1], (unsigned)r57[1]};
  out[0] = __builtin_bit_cast(h8_t, w0);
  out[1] = __builtin_bit_cast(h8_t, w1);
}

__global__ __launch_bounds__(256, 2) void attn_kernel(
    const _Float16* __restrict__ Q, const _Float16* __restrict__ K,
    const _Float16* __restrict__ Vt, _Float16* __restrict__ O) {
  __shared__ _Float16 Kl[2][64 * 64];
  __shared__ _Float16 Vl[2][64 * 64];
  const int tid = threadIdx.x;
  const int lane = tid & 63;
  const int w = tid >> 6;
  const int hi = lane >> 5;
  const int l31 = lane & 31;
  const int bh = blockIdx.x >> 3;
  const int pr = blockIdx.x & 7;
  const int b = bh >> 4, h = bh & 15;
  const _Float16* Kbh = K + (size_t)bh * 2048 * 64;
  const _Float16* Vbh = Vt + (size_t)bh * 64 * 2048;

#pragma unroll
  for (int gi = 0; gi < 2; ++gi) {
    const int g = gi ? (15 - pr) : pr;
    const int nt = 2 * g + 2;
    const int qbase = g * 128 + w * 32;
    const int qrow = qbase + l31;

    h8_t qf[4];
    const _Float16* Qp = Q + ((size_t)bh * 2048 + qrow) * 64 + hi * 8;
#pragma unroll
    for (int ds = 0; ds < 4; ++ds)
      qf[ds] = *reinterpret_cast<const h8_t*>(Qp + ds * 16);

    f32x16 oa[2] = {};
    float m = -1e30f, lsum = 0.f;

    stage_kv(Kbh, Vbh, 0, &Kl[0][0], &Vl[0][0], w, lane);
    __syncthreads();

    for (int kt = 0; kt < nt; ++kt) {
      const int cur = kt & 1;
      if (kt + 1 < nt)
        stage_kv(Kbh, Vbh, kt + 1, &Kl[cur ^ 1][0], &Vl[cur ^ 1][0], w, lane);

      if (kt * 64 <= qbase + 31) {
        const char* Kb = (const char*)&Kl[cur][0];
        const char* Vb = (const char*)&Vl[cur][0];
        f32x16 s0 = {}, s1 = {};
#pragma unroll
        for (int ds = 0; ds < 4; ++ds) {
          const int bc = ds * 32 + hi * 16;
          h8_t kf0 = *(const h8_t*)(Kb + l31 * 128 + (bc ^ ((l31 & 7) << 4)));
          h8_t kf1 = *(const h8_t*)(Kb + (32 + l31) * 128 + (bc ^ ((l31 & 7) << 4)));
          s0 = MFMA_32x32x16_F16(kf0, qf[ds], s0);
          s1 = MFMA_32x32x16_F16(kf1, qf[ds], s1);
        }
        if (kt >= 2 * g) {
#pragma unroll
          for (int r = 0; r < 16; ++r) {
            const int kr = kt * 64 + (r & 3) + 8 * (r >> 2) + 4 * hi;
            if (kr > qrow) s0[r] = -1e30f;
            if (kr + 32 > qrow) s1[r] = -1e30f;
          }
        }
        float t[16];
#pragma unroll
        for (int r = 0; r < 16; ++r) t[r] = fmaxf(s0[r], s1[r]);
#pragma unroll
        for (int st = 8; st >= 1; st >>= 1)
#pragma unroll
          for (int r = 0; r < st; ++r) t[r] = fmaxf(t[r], t[r + st]);
        const float pmax = fmaxf(t[0], __shfl_xor(t[0], 32));
        const float mnew = fmaxf(m, pmax);
        if (__any(mnew > m + 8.f)) {
          const float al = __builtin_amdgcn_exp2f(m - mnew);
          lsum *= al;
#pragma unroll
          for (int r = 0; r < 16; ++r) { oa[0][r] *= al; oa[1][r] *= al; }
          m = mnew;
        }
        float e0[16], e1[16];
#pragma unroll
        for (int r = 0; r < 16; ++r) {
          e0[r] = __builtin_amdgcn_exp2f(s0[r] - m);
          e1[r] = __builtin_amdgcn_exp2f(s1[r] - m);
        }
        float ps = 0.f;
#pragma unroll
        for (int r = 0; r < 16; ++r) ps += e0[r] + e1[r];
        ps += __shfl_xor(ps, 32);
        lsum += ps;
        h8_t pf[4];
        pack_pfrag(e0, pf + 0);
        pack_pfrag(e1, pf + 2);
#pragma unroll
        for (int dt = 0; dt < 2; ++dt) {
#pragma unroll
          for (int kg = 0; kg < 4; ++kg) {
            const int row = dt * 32 + l31;
            const int bc = kg * 32 + hi * 16;
            h8_t vf = *(const h8_t*)(Vb + row * 128 + (bc ^ ((row & 7) << 4)));
            oa[dt] = MFMA_32x32x16_F16(vf, pf[kg], oa[dt]);
          }
        }
      }
      __syncthreads();
    }

    const float inv = __builtin_amdgcn_rcpf(lsum);
    _Float16* Op = O + ((size_t)b * 2048 + qrow) * 1024 + h * 64;
#pragma unroll
    for (int dt = 0; dt < 2; ++dt) {
#pragma unroll
      for (int rg = 0; rg < 4; ++rg) {
        h4_t pk4;
#pragma unroll
        for (int i = 0; i < 4; ++i) pk4[i] = (_Float16)(oa[dt][rg * 4 + i] * inv);
        *reinterpret_cast<h4_t*>(Op + dt * 32 + rg * 8 + hi * 4) = pk4;
      }
    }
  }
}

extern "C" void kernel_launch(void* const* d_in, const int* in_sizes, int n_in,
                              void* d_out, int out_size, void* d_ws, size_t ws_size,
                              hipStream_t stream) {
  (void)in_sizes; (void)n_in; (void)out_size; (void)ws_size;
  const float* x = (const float*)d_in[0];
  const float* w_qkv = (const float*)d_in[1];
  const float* b_qkv = (const float*)d_in[2];
  const float* w_out = (const float*)d_in[3];
  const float* b_out = (const float*)d_in[4];
  float* out = (float*)d_out;

  char* ws = (char*)d_ws;
  size_t off = 0;
  auto alloc = [&](size_t bytes) {
    void* p = ws + off;
    off += (bytes + 255) & ~(size_t)255;
    return p;
  };
  _Float16* x16 = (_Float16*)alloc((size_t)8192 * 1024 * 2);
  _Float16* wqkvT = (_Float16*)alloc((size_t)3072 * 1024 * 2);
  _Float16* woutT = (_Float16*)alloc((size_t)1024 * 1024 * 2);
  _Float16* Qh = (_Float16*)alloc((size_t)64 * 2048 * 64 * 2);
  _Float16* Kh = (_Float16*)alloc((size_t)64 * 2048 * 64 * 2);
  _Float16* Vth = (_Float16*)alloc((size_t)64 * 64 * 2048 * 2);
  _Float16* Oh = (_Float16*)alloc((size_t)8192 * 1024 * 2);

  cvt_f16_kernel<<<8192, 256, 0, stream>>>(x, x16, 8192 * 1024 / 4);
  transpose_cvt_kernel<<<dim3(3072 / 32, 1024 / 32), 256, 0, stream>>>(w_qkv, wqkvT, 1024, 3072);
  transpose_cvt_kernel<<<dim3(1024 / 32, 1024 / 32), 256, 0, stream>>>(w_out, woutT, 1024, 1024);
  gemm_bt_kernel<0><<<64 * 24, 256, 0, stream>>>(x16, wqkvT, b_qkv, Qh, Kh, Vth, nullptr, 24);
  attn_kernel<<<64 * 8, 256, 0, stream>>>(Qh, Kh, Vth, Oh);
  gemm_bt_kernel<1><<<64 * 8, 256, 0, stream>>>(Oh, woutT, b_out, nullptr, nullptr, nullptr, out, 8);
}

// Round 9
// 179.099 us; speedup vs baseline: 1.2042x; 1.0284x over previous
//
#include <hip/hip_runtime.h>
#include <cstdint>
#include <cstddef>

typedef _Float16 h8_t __attribute__((ext_vector_type(8)));
typedef _Float16 h4_t __attribute__((ext_vector_type(4)));
typedef float f32x4 __attribute__((ext_vector_type(4)));
typedef float f32x16 __attribute__((ext_vector_type(16)));
typedef unsigned u32x4 __attribute__((ext_vector_type(4)));

#define MFMA_16x16x32_F16(a, b, c) __builtin_amdgcn_mfma_f32_16x16x32_f16(a, b, c, 0, 0, 0)
#define MFMA_32x32x16_F16(a, b, c) __builtin_amdgcn_mfma_f32_32x32x16_f16(a, b, c, 0, 0, 0)

__device__ inline void gload_lds16(const void* g, void* l) {
  __builtin_amdgcn_global_load_lds((const __attribute__((address_space(1))) void*)g,
                                   (__attribute__((address_space(3))) void*)l, 16, 0, 0);
}

#define CFENCE asm volatile("" ::: "memory")
#define RAW_BAR() do { CFENCE; __builtin_amdgcn_s_barrier(); CFENCE; } while (0)

// ---------------- convert f32 -> f16 ----------------
__global__ void cvt_f16_kernel(const float* __restrict__ in, _Float16* __restrict__ out, int n4) {
  int i = blockIdx.x * 256 + threadIdx.x;
  if (i >= n4) return;
  float4 v = reinterpret_cast<const float4*>(in)[i];
  h4_t h;
  h[0] = (_Float16)v.x; h[1] = (_Float16)v.y; h[2] = (_Float16)v.z; h[3] = (_Float16)v.w;
  reinterpret_cast<h4_t*>(out)[i] = h;
}

// ---------------- transpose + convert: in[R][Cc] f32 -> out[Cc][R] f16 ----------------
__global__ void transpose_cvt_kernel(const float* __restrict__ in, _Float16* __restrict__ out,
                                     int R, int Cc) {
  __shared__ float tile[32][33];
  int tx = threadIdx.x & 31;
  int ty = threadIdx.x >> 5;
  int c0 = blockIdx.x * 32;
  int r0 = blockIdx.y * 32;
#pragma unroll
  for (int i = 0; i < 4; ++i)
    tile[ty + i * 8][tx] = in[(size_t)(r0 + ty + i * 8) * Cc + (c0 + tx)];
  __syncthreads();
#pragma unroll
  for (int i = 0; i < 4; ++i)
    out[(size_t)(c0 + ty + i * 8) * R + (r0 + tx)] = (_Float16)tile[tx][ty + i * 8];
}

// ============ QKV GEMM: 256x384 tile, 8 waves (2x4), 2-phase/K-tile, triple-buffer ======
// Grid = 32 x 8 = 256 blocks = exactly 1/CU, one round. Natural order: bn = blk%8 -> XCD,
// so each XCD's single B-panel (384x1024 f16 = 768KB) stays L2-resident.
// Per wave: 128x96 output (acc[8][6]), 48 MFMA per K-tile (BK=32, single kk).
// LDS fragment-major (0-conflict): A slot ((fg)*64+lane)*8 holds A[fg*16+(lane&15)][(lane>>4)*8..+7].
// Schedule per K-tile t: ph0 {read A0..3 + B0..5 (10 b128) | stageA(t+2) 2u | bar | lgkm0 |
// prio1 24 MFMA prio0 | bar}; ph1 {read A4..7 | stageB(t+2) 3u | bar | lgkm0 | prio1 24 MFMA
// prio0 | vmcnt(5) bar}. vmcnt(5) = t+2's 5 units in flight, t+1 landed. Never vmcnt(0) mid-loop.
// Buf write (t+2) vs last read (t-1) separated by >=1 barrier.
__global__ __launch_bounds__(512, 2) void gemm_qkv_kernel(
    const _Float16* __restrict__ A, const _Float16* __restrict__ Bt,
    const float* __restrict__ bias, _Float16* __restrict__ outQ,
    _Float16* __restrict__ outK, _Float16* __restrict__ outV) {
  __shared__ _Float16 Al[3][8192];   // 256x32 f16, fragment-major
  __shared__ _Float16 Bl[3][12288];  // 384x32 f16

  const int tid = threadIdx.x;
  const int lane = tid & 63;
  const int w = tid >> 6;
  const int wm = w >> 2, wn = w & 3;
  const int bm = blockIdx.x >> 3;
  const int bn = blockIdx.x & 7;
  const int m0 = bm * 256;
  const int n0 = bn * 384;

  f32x4 acc[8][6];
#pragma unroll
  for (int i = 0; i < 8; ++i)
#pragma unroll
    for (int j = 0; j < 6; ++j) acc[i][j] = (f32x4){0.f, 0.f, 0.f, 0.f};

  // staging unit 0 addressing (units u add fg+=8 -> row += 128 -> +131072 elems; dst += 4096)
  const int fg0 = tid >> 6;         // 0..7
  const int sl = tid & 63;
  const int srow = fg0 * 16 + (sl & 15);
  const int scol = (sl >> 4) * 8;
  const _Float16* aS = A + (size_t)(m0 + srow) * 1024 + scol;
  const _Float16* bS = Bt + (size_t)(n0 + srow) * 1024 + scol;
  const int sdst = tid * 8;

  auto stageA = [&](int buf, int kt) {
    const int k0 = kt * 32;
    gload_lds16(aS + k0, &Al[buf][sdst]);
    gload_lds16(aS + 131072 + k0, &Al[buf][sdst + 4096]);
  };
  auto stageB = [&](int buf, int kt) {
    const int k0 = kt * 32;
    gload_lds16(bS + k0, &Bl[buf][sdst]);
    gload_lds16(bS + 131072 + k0, &Bl[buf][sdst + 4096]);
    gload_lds16(bS + 262144 + k0, &Bl[buf][sdst + 8192]);
  };

  const int offA0 = (wm * 8 * 64 + lane) * 8;   // + mf*512*8? no: +mf*(64*8)=mf*512
  const int offB0 = (wn * 6 * 64 + lane) * 8;

  // prologue: stage tiles 0,1 (10 units); wait tile 0 (5 remain in flight)
  stageA(0, 0); stageB(0, 0);
  stageA(1, 1); stageB(1, 1);
  asm volatile("s_waitcnt vmcnt(5)" ::: "memory");
  RAW_BAR();

  int cur = 0;
#pragma unroll 1
  for (int t = 0; t < 32; ++t) {
    int nb = cur + 2; if (nb >= 3) nb -= 3;
    const bool st = (t + 2) < 32;
    const _Float16* Ab = &Al[cur][0];
    const _Float16* Bb = &Bl[cur][0];
    h8_t af[4], bf[6];

    // ---- phase 0: A-frags 0..3 + all B-frags; stage A of t+2; MFMA m0..3 x n0..5
#pragma unroll
    for (int mf = 0; mf < 4; ++mf) af[mf] = *(const h8_t*)&Ab[offA0 + mf * 512];
#pragma unroll
    for (int nf = 0; nf < 6; ++nf) bf[nf] = *(const h8_t*)&Bb[offB0 + nf * 512];
    if (st) stageA(nb, t + 2);
    RAW_BAR();
    asm volatile("s_waitcnt lgkmcnt(0)" ::: "memory");
    __builtin_amdgcn_sched_barrier(0);
    __builtin_amdgcn_s_setprio(1);
#pragma unroll
    for (int mf = 0; mf < 4; ++mf)
#pragma unroll
      for (int nf = 0; nf < 6; ++nf)
        acc[mf][nf] = MFMA_16x16x32_F16(af[mf], bf[nf], acc[mf][nf]);
    __builtin_amdgcn_s_setprio(0);
    RAW_BAR();

    // ---- phase 1: A-frags 4..7; stage B of t+2; MFMA m4..7 x n0..5; counted vmcnt
#pragma unroll
    for (int mf = 0; mf < 4; ++mf) af[mf] = *(const h8_t*)&Ab[offA0 + (4 + mf) * 512];
    if (st) stageB(nb, t + 2);
    RAW_BAR();
    asm volatile("s_waitcnt lgkmcnt(0)" ::: "memory");
    __builtin_amdgcn_sched_barrier(0);
    __builtin_amdgcn_s_setprio(1);
#pragma unroll
    for (int mf = 0; mf < 4; ++mf)
#pragma unroll
      for (int nf = 0; nf < 6; ++nf)
        acc[4 + mf][nf] = MFMA_16x16x32_F16(af[mf], bf[nf], acc[4 + mf][nf]);
    __builtin_amdgcn_s_setprio(0);
    if (t < 31) {
      if (st) asm volatile("s_waitcnt vmcnt(5)" ::: "memory");
      else asm volatile("s_waitcnt vmcnt(0)" ::: "memory");
      RAW_BAR();
    }
    ++cur; if (cur == 3) cur = 0;
  }

  // ---- epilogue: route Q (scaled, exp2-ready), K, V^T
  const int gm0 = m0 + wm * 128;
  const int gn0 = n0 + wn * 96;
#pragma unroll
  for (int mf = 0; mf < 8; ++mf) {
#pragma unroll
    for (int nf = 0; nf < 6; ++nf) {
      const int gn = gn0 + nf * 16 + (lane & 15);
      const int tm0 = gm0 + mf * 16 + (lane >> 4) * 4;
      const float bv = bias[gn];
      const int which = gn >> 10;  // 0=Q 1=K 2=V
      const int nn = gn & 1023;
      const int h = nn >> 6, d = nn & 63;
      const int t0 = tm0 & 2047, b = tm0 >> 11;
      const int bh = b * 16 + h;
      if (which == 2) {
        h4_t pack;
#pragma unroll
        for (int r = 0; r < 4; ++r) pack[r] = (_Float16)(acc[mf][nf][r] + bv);
        *reinterpret_cast<h4_t*>(&outV[((size_t)bh * 64 + d) * 2048 + t0]) = pack;
      } else {
        _Float16* dst = (which == 0) ? outQ : outK;
        // Q pre-scaled by log2(e)/sqrt(D) so attention can use exp2 directly
        const float scale = (which == 0) ? 0.18033688011112042f : 1.0f;
#pragma unroll
        for (int r = 0; r < 4; ++r)
          dst[((size_t)bh * 2048 + t0 + r) * 64 + d] = (_Float16)((acc[mf][nf][r] + bv) * scale);
      }
    }
  }
}

// ---------------- out-proj GEMM (R8-proven): 128x128, BK=32, triple-buffer counted vmcnt ---
__global__ __launch_bounds__(256, 3) void gemm_out_kernel(
    const _Float16* __restrict__ A, const _Float16* __restrict__ Bt,
    const float* __restrict__ bias, float* __restrict__ outF, int NB) {
  __shared__ _Float16 Al[3][4096];
  __shared__ _Float16 Bl[3][4096];
  const int tid = threadIdx.x;
  const int lane = tid & 63;
  const int w = tid >> 6;
  const int bm = blockIdx.x / NB;
  const int bn = blockIdx.x % NB;
  const int wm = w & 1, wn = w >> 1;
  const int m0 = bm * 128, n0 = bn * 128;

  f32x4 acc[4][4];
#pragma unroll
  for (int m = 0; m < 4; ++m)
#pragma unroll
    for (int n = 0; n < 4; ++n) acc[m][n] = (f32x4){0.f, 0.f, 0.f, 0.f};

  const int seg0 = w * 2, seg1 = w * 2 + 1;
  const int r0s = seg0 * 16 + (lane >> 2);
  const int r1s = seg1 * 16 + (lane >> 2);
  const int c0s = ((lane & 3) ^ ((r0s >> 1) & 3)) * 8;
  const int c1s = ((lane & 3) ^ ((r1s >> 1) & 3)) * 8;
  const _Float16* aS0 = A + (size_t)(m0 + r0s) * 1024 + c0s;
  const _Float16* aS1 = A + (size_t)(m0 + r1s) * 1024 + c1s;
  const _Float16* bS0 = Bt + (size_t)(n0 + r0s) * 1024 + c0s;
  const _Float16* bS1 = Bt + (size_t)(n0 + r1s) * 1024 + c1s;
  const int d0 = seg0 * 512 + lane * 8;
  const int d1 = seg1 * 512 + lane * 8;

  auto stage = [&](int buf, int kt) {
    const int k0 = kt * 32;
    gload_lds16(aS0 + k0, &Al[buf][d0]);
    gload_lds16(bS0 + k0, &Bl[buf][d0]);
    gload_lds16(aS1 + k0, &Al[buf][d1]);
    gload_lds16(bS1 + k0, &Bl[buf][d1]);
  };

  int offA[4], offB[4];
#pragma unroll
  for (int i = 0; i < 4; ++i) {
    const int rowA = wm * 64 + i * 16 + (lane & 15);
    offA[i] = rowA * 32 + (((lane >> 4) ^ ((rowA >> 1) & 3)) * 8);
    const int rowB = wn * 64 + i * 16 + (lane & 15);
    offB[i] = rowB * 32 + (((lane >> 4) ^ ((rowB >> 1) & 3)) * 8);
  }

  stage(0, 0);
  stage(1, 1);
  asm volatile("s_waitcnt vmcnt(4)" ::: "memory");
  RAW_BAR();

  int cur = 0;
#pragma unroll 1
  for (int t = 0; t < 32; ++t) {
    int nb = cur + 2; if (nb >= 3) nb -= 3;
    if (t + 2 < 32) stage(nb, t + 2);
    const _Float16* Ab = &Al[cur][0];
    const _Float16* Bb = &Bl[cur][0];
    h8_t af[4], bf[4];
#pragma unroll
    for (int i = 0; i < 4; ++i) af[i] = *(const h8_t*)&Ab[offA[i]];
#pragma unroll
    for (int j = 0; j < 4; ++j) bf[j] = *(const h8_t*)&Bb[offB[j]];
#pragma unroll
    for (int i = 0; i < 4; ++i)
#pragma unroll
      for (int j = 0; j < 4; ++j)
        acc[i][j] = MFMA_16x16x32_F16(af[i], bf[j], acc[i][j]);
    if (t < 31) {
      if (t + 2 < 32) asm volatile("s_waitcnt vmcnt(4)" ::: "memory");
      else asm volatile("s_waitcnt vmcnt(0)" ::: "memory");
      RAW_BAR();
    }
    ++cur; if (cur == 3) cur = 0;
  }

  const int gm0 = bm * 128 + wm * 64;
  const int gn0 = bn * 128 + wn * 64;
#pragma unroll
  for (int i = 0; i < 4; ++i) {
#pragma unroll
    for (int j = 0; j < 4; ++j) {
      const int gn = gn0 + j * 16 + (lane & 15);
      const int tm0 = gm0 + i * 16 + (lane >> 4) * 4;
      const float bv = bias[gn];
#pragma unroll
      for (int r = 0; r < 4; ++r)
        outF[(size_t)(tm0 + r) * 1024 + gn] = acc[i][j][r] + bv;
    }
  }
}

// ---------------- flash attention (causal), swapped-QK in-register softmax ----------------
__device__ inline void stage_kv(const _Float16* __restrict__ Kbh, const _Float16* __restrict__ Vbh,
                                int kt, _Float16* Kd, _Float16* Vd, int w, int lane) {
  const _Float16* Kg = Kbh + (size_t)kt * 64 * 64;
  const _Float16* Vg = Vbh + kt * 64;
#pragma unroll
  for (int c = 0; c < 2; ++c) {
    const int idx = (2 * w + c) * 64 + lane;
    const int row = idx >> 3;
    const int chs = (idx & 7) ^ (row & 7);  // pre-swizzled global source (T2 via m173)
    gload_lds16(Kg + row * 64 + chs * 8, Kd + idx * 8);
    gload_lds16(Vg + (size_t)row * 2048 + chs * 8, Vd + idx * 8);
  }
}

// pack 16 exp'd f32 into 2 PV B-fragments
__device__ inline void pack_pfrag(const float* e, h8_t* out) {
  unsigned u[8];
#pragma unroll
  for (int i = 0; i < 8; ++i) {
    auto hv = __builtin_amdgcn_cvt_pkrtz(e[2 * i], e[2 * i + 1]);
    u[i] = __builtin_bit_cast(unsigned, hv);
  }
  auto r02 = __builtin_amdgcn_permlane32_swap(u[0], u[2], false, false);
  auto r13 = __builtin_amdgcn_permlane32_swap(u[1], u[3], false, false);
  auto r46 = __builtin_amdgcn_permlane32_swap(u[4], u[6], false, false);
  auto r57 = __builtin_amdgcn_permlane32_swap(u[5], u[7], false, false);
  u32x4 w0 = {(unsigned)r02[0], (unsigned)r13[0], (unsigned)r02[1], (unsigned)r13[1]};
  u32x4 w1 = {(unsigned)r46[0], (unsigned)r57[0], (unsigned)r46[1], (unsigned)r57[1]};
  out[0] = __builtin_bit_cast(h8_t, w0);
  out[1] = __builtin_bit_cast(h8_t, w1);
}

__global__ __launch_bounds__(256, 2) void attn_kernel(
    const _Float16* __restrict__ Q, const _Float16* __restrict__ K,
    const _Float16* __restrict__ Vt, _Float16* __restrict__ O) {
  __shared__ _Float16 Kl[2][64 * 64];
  __shared__ _Float16 Vl[2][64 * 64];
  const int tid = threadIdx.x;
  const int lane = tid & 63;
  const int w = tid >> 6;
  const int hi = lane >> 5;
  const int l31 = lane & 31;
  const int bh = blockIdx.x >> 3;
  const int pr = blockIdx.x & 7;
  const int b = bh >> 4, h = bh & 15;
  const _Float16* Kbh = K + (size_t)bh * 2048 * 64;
  const _Float16* Vbh = Vt + (size_t)bh * 64 * 2048;

#pragma unroll
  for (int gi = 0; gi < 2; ++gi) {
    const int g = gi ? (15 - pr) : pr;
    const int nt = 2 * g + 2;
    const int qbase = g * 128 + w * 32;
    const int qrow = qbase + l31;

    h8_t qf[4];
    const _Float16* Qp = Q + ((size_t)bh * 2048 + qrow) * 64 + hi * 8;
#pragma unroll
    for (int ds = 0; ds < 4; ++ds)
      qf[ds] = *reinterpret_cast<const h8_t*>(Qp + ds * 16);

    f32x16 oa[2] = {};
    float m = -1e30f, lsum = 0.f;

    stage_kv(Kbh, Vbh, 0, &Kl[0][0], &Vl[0][0], w, lane);
    __syncthreads();

    for (int kt = 0; kt < nt; ++kt) {
      const int cur = kt & 1;
      if (kt + 1 < nt)
        stage_kv(Kbh, Vbh, kt + 1, &Kl[cur ^ 1][0], &Vl[cur ^ 1][0], w, lane);

      if (kt * 64 <= qbase + 31) {
        const char* Kb = (const char*)&Kl[cur][0];
        const char* Vb = (const char*)&Vl[cur][0];
        f32x16 s0 = {}, s1 = {};
#pragma unroll
        for (int ds = 0; ds < 4; ++ds) {
          const int bc = ds * 32 + hi * 16;
          h8_t kf0 = *(const h8_t*)(Kb + l31 * 128 + (bc ^ ((l31 & 7) << 4)));
          h8_t kf1 = *(const h8_t*)(Kb + (32 + l31) * 128 + (bc ^ ((l31 & 7) << 4)));
          s0 = MFMA_32x32x16_F16(kf0, qf[ds], s0);
          s1 = MFMA_32x32x16_F16(kf1, qf[ds], s1);
        }
        if (kt >= 2 * g) {
#pragma unroll
          for (int r = 0; r < 16; ++r) {
            const int kr = kt * 64 + (r & 3) + 8 * (r >> 2) + 4 * hi;
            if (kr > qrow) s0[r] = -1e30f;
            if (kr + 32 > qrow) s1[r] = -1e30f;
          }
        }
        float t[16];
#pragma unroll
        for (int r = 0; r < 16; ++r) t[r] = fmaxf(s0[r], s1[r]);
#pragma unroll
        for (int st = 8; st >= 1; st >>= 1)
#pragma unroll
          for (int r = 0; r < st; ++r) t[r] = fmaxf(t[r], t[r + st]);
        const float pmax = fmaxf(t[0], __shfl_xor(t[0], 32));
        const float mnew = fmaxf(m, pmax);
        if (__any(mnew > m + 8.f)) {
          const float al = __builtin_amdgcn_exp2f(m - mnew);
          lsum *= al;
#pragma unroll
          for (int r = 0; r < 16; ++r) { oa[0][r] *= al; oa[1][r] *= al; }
          m = mnew;
        }
        float e0[16], e1[16];
#pragma unroll
        for (int r = 0; r < 16; ++r) {
          e0[r] = __builtin_amdgcn_exp2f(s0[r] - m);
          e1[r] = __builtin_amdgcn_exp2f(s1[r] - m);
        }
        float ps = 0.f;
#pragma unroll
        for (int r = 0; r < 16; ++r) ps += e0[r] + e1[r];
        ps += __shfl_xor(ps, 32);
        lsum += ps;
        h8_t pf[4];
        pack_pfrag(e0, pf + 0);
        pack_pfrag(e1, pf + 2);
#pragma unroll
        for (int dt = 0; dt < 2; ++dt) {
#pragma unroll
          for (int kg = 0; kg < 4; ++kg) {
            const int row = dt * 32 + l31;
            const int bc = kg * 32 + hi * 16;
            h8_t vf = *(const h8_t*)(Vb + row * 128 + (bc ^ ((row & 7) << 4)));
            oa[dt] = MFMA_32x32x16_F16(vf, pf[kg], oa[dt]);
          }
        }
      }
      __syncthreads();
    }

    const float inv = __builtin_amdgcn_rcpf(lsum);
    _Float16* Op = O + ((size_t)b * 2048 + qrow) * 1024 + h * 64;
#pragma unroll
    for (int dt = 0; dt < 2; ++dt) {
#pragma unroll
      for (int rg = 0; rg < 4; ++rg) {
        h4_t pk4;
#pragma unroll
        for (int i = 0; i < 4; ++i) pk4[i] = (_Float16)(oa[dt][rg * 4 + i] * inv);
        *reinterpret_cast<h4_t*>(Op + dt * 32 + rg * 8 + hi * 4) = pk4;
      }
    }
  }
}

extern "C" void kernel_launch(void* const* d_in, const int* in_sizes, int n_in,
                              void* d_out, int out_size, void* d_ws, size_t ws_size,
                              hipStream_t stream) {
  (void)in_sizes; (void)n_in; (void)out_size; (void)ws_size;
  const float* x = (const float*)d_in[0];
  const float* w_qkv = (const float*)d_in[1];
  const float* b_qkv = (const float*)d_in[2];
  const float* w_out = (const float*)d_in[3];
  const float* b_out = (const float*)d_in[4];
  float* out = (float*)d_out;

  char* ws = (char*)d_ws;
  size_t off = 0;
  auto alloc = [&](size_t bytes) {
    void* p = ws + off;
    off += (bytes + 255) & ~(size_t)255;
    return p;
  };
  _Float16* x16 = (_Float16*)alloc((size_t)8192 * 1024 * 2);
  _Float16* wqkvT = (_Float16*)alloc((size_t)3072 * 1024 * 2);
  _Float16* woutT = (_Float16*)alloc((size_t)1024 * 1024 * 2);
  _Float16* Qh = (_Float16*)alloc((size_t)64 * 2048 * 64 * 2);
  _Float16* Kh = (_Float16*)alloc((size_t)64 * 2048 * 64 * 2);
  _Float16* Vth = (_Float16*)alloc((size_t)64 * 64 * 2048 * 2);
  _Float16* Oh = (_Float16*)alloc((size_t)8192 * 1024 * 2);

  cvt_f16_kernel<<<8192, 256, 0, stream>>>(x, x16, 8192 * 1024 / 4);
  transpose_cvt_kernel<<<dim3(3072 / 32, 1024 / 32), 256, 0, stream>>>(w_qkv, wqkvT, 1024, 3072);
  transpose_cvt_kernel<<<dim3(1024 / 32, 1024 / 32), 256, 0, stream>>>(w_out, woutT, 1024, 1024);
  gemm_qkv_kernel<<<256, 512, 0, stream>>>(x16, wqkvT, b_qkv, Qh, Kh, Vth);
  attn_kernel<<<64 * 8, 256, 0, stream>>>(Qh, Kh, Vth, Oh);
  gemm_out_kernel<<<64 * 8, 256, 0, stream>>>(Oh, woutT, b_out, out, 8);
}

// Round 10
// 177.629 us; speedup vs baseline: 1.2142x; 1.0083x over previous
//
#include <hip/hip_runtime.h>
#include <cstdint>
#include <cstddef>

typedef _Float16 h8_t __attribute__((ext_vector_type(8)));
typedef _Float16 h4_t __attribute__((ext_vector_type(4)));
typedef float f32x4 __attribute__((ext_vector_type(4)));
typedef float f32x16 __attribute__((ext_vector_type(16)));
typedef unsigned u32x4 __attribute__((ext_vector_type(4)));

#define MFMA_16x16x32_F16(a, b, c) __builtin_amdgcn_mfma_f32_16x16x32_f16(a, b, c, 0, 0, 0)
#define MFMA_32x32x16_F16(a, b, c) __builtin_amdgcn_mfma_f32_32x32x16_f16(a, b, c, 0, 0, 0)

__device__ inline void gload_lds16(const void* g, void* l) {
  __builtin_amdgcn_global_load_lds((const __attribute__((address_space(1))) void*)g,
                                   (__attribute__((address_space(3))) void*)l, 16, 0, 0);
}

#define CFENCE asm volatile("" ::: "memory")
#define RAW_BAR() do { CFENCE; __builtin_amdgcn_s_barrier(); CFENCE; } while (0)

// ---------------- convert f32 -> f16 ----------------
__global__ void cvt_f16_kernel(const float* __restrict__ in, _Float16* __restrict__ out, int n4) {
  int i = blockIdx.x * 256 + threadIdx.x;
  if (i >= n4) return;
  float4 v = reinterpret_cast<const float4*>(in)[i];
  h4_t h;
  h[0] = (_Float16)v.x; h[1] = (_Float16)v.y; h[2] = (_Float16)v.z; h[3] = (_Float16)v.w;
  reinterpret_cast<h4_t*>(out)[i] = h;
}

// ---------------- transpose + convert: in[R][Cc] f32 -> out[Cc][R] f16 ----------------
__global__ void transpose_cvt_kernel(const float* __restrict__ in, _Float16* __restrict__ out,
                                     int R, int Cc) {
  __shared__ float tile[32][33];
  int tx = threadIdx.x & 31;
  int ty = threadIdx.x >> 5;
  int c0 = blockIdx.x * 32;
  int r0 = blockIdx.y * 32;
#pragma unroll
  for (int i = 0; i < 4; ++i)
    tile[ty + i * 8][tx] = in[(size_t)(r0 + ty + i * 8) * Cc + (c0 + tx)];
  __syncthreads();
#pragma unroll
  for (int i = 0; i < 4; ++i)
    out[(size_t)(c0 + ty + i * 8) * R + (r0 + tx)] = (_Float16)tile[tx][ty + i * 8];
}

// ============ QKV GEMM (R9, kept): 256x384 tile, 8 waves, 2-phase/K-tile, triple-buffer ===
__global__ __launch_bounds__(512, 2) void gemm_qkv_kernel(
    const _Float16* __restrict__ A, const _Float16* __restrict__ Bt,
    const float* __restrict__ bias, _Float16* __restrict__ outQ,
    _Float16* __restrict__ outK, _Float16* __restrict__ outV) {
  __shared__ _Float16 Al[3][8192];
  __shared__ _Float16 Bl[3][12288];

  const int tid = threadIdx.x;
  const int lane = tid & 63;
  const int w = tid >> 6;
  const int wm = w >> 2, wn = w & 3;
  const int bm = blockIdx.x >> 3;
  const int bn = blockIdx.x & 7;
  const int m0 = bm * 256;
  const int n0 = bn * 384;

  f32x4 acc[8][6];
#pragma unroll
  for (int i = 0; i < 8; ++i)
#pragma unroll
    for (int j = 0; j < 6; ++j) acc[i][j] = (f32x4){0.f, 0.f, 0.f, 0.f};

  const int fg0 = tid >> 6;
  const int sl = tid & 63;
  const int srow = fg0 * 16 + (sl & 15);
  const int scol = (sl >> 4) * 8;
  const _Float16* aS = A + (size_t)(m0 + srow) * 1024 + scol;
  const _Float16* bS = Bt + (size_t)(n0 + srow) * 1024 + scol;
  const int sdst = tid * 8;

  auto stageA = [&](int buf, int kt) {
    const int k0 = kt * 32;
    gload_lds16(aS + k0, &Al[buf][sdst]);
    gload_lds16(aS + 131072 + k0, &Al[buf][sdst + 4096]);
  };
  auto stageB = [&](int buf, int kt) {
    const int k0 = kt * 32;
    gload_lds16(bS + k0, &Bl[buf][sdst]);
    gload_lds16(bS + 131072 + k0, &Bl[buf][sdst + 4096]);
    gload_lds16(bS + 262144 + k0, &Bl[buf][sdst + 8192]);
  };

  const int offA0 = (wm * 8 * 64 + lane) * 8;
  const int offB0 = (wn * 6 * 64 + lane) * 8;

  stageA(0, 0); stageB(0, 0);
  stageA(1, 1); stageB(1, 1);
  asm volatile("s_waitcnt vmcnt(5)" ::: "memory");
  RAW_BAR();

  int cur = 0;
#pragma unroll 1
  for (int t = 0; t < 32; ++t) {
    int nb = cur + 2; if (nb >= 3) nb -= 3;
    const bool st = (t + 2) < 32;
    const _Float16* Ab = &Al[cur][0];
    const _Float16* Bb = &Bl[cur][0];
    h8_t af[4], bf[6];

#pragma unroll
    for (int mf = 0; mf < 4; ++mf) af[mf] = *(const h8_t*)&Ab[offA0 + mf * 512];
#pragma unroll
    for (int nf = 0; nf < 6; ++nf) bf[nf] = *(const h8_t*)&Bb[offB0 + nf * 512];
    if (st) stageA(nb, t + 2);
    RAW_BAR();
    asm volatile("s_waitcnt lgkmcnt(0)" ::: "memory");
    __builtin_amdgcn_sched_barrier(0);
    __builtin_amdgcn_s_setprio(1);
#pragma unroll
    for (int mf = 0; mf < 4; ++mf)
#pragma unroll
      for (int nf = 0; nf < 6; ++nf)
        acc[mf][nf] = MFMA_16x16x32_F16(af[mf], bf[nf], acc[mf][nf]);
    __builtin_amdgcn_s_setprio(0);
    RAW_BAR();

#pragma unroll
    for (int mf = 0; mf < 4; ++mf) af[mf] = *(const h8_t*)&Ab[offA0 + (4 + mf) * 512];
    if (st) stageB(nb, t + 2);
    RAW_BAR();
    asm volatile("s_waitcnt lgkmcnt(0)" ::: "memory");
    __builtin_amdgcn_sched_barrier(0);
    __builtin_amdgcn_s_setprio(1);
#pragma unroll
    for (int mf = 0; mf < 4; ++mf)
#pragma unroll
      for (int nf = 0; nf < 6; ++nf)
        acc[4 + mf][nf] = MFMA_16x16x32_F16(af[mf], bf[nf], acc[4 + mf][nf]);
    __builtin_amdgcn_s_setprio(0);
    if (t < 31) {
      if (st) asm volatile("s_waitcnt vmcnt(5)" ::: "memory");
      else asm volatile("s_waitcnt vmcnt(0)" ::: "memory");
      RAW_BAR();
    }
    ++cur; if (cur == 3) cur = 0;
  }

  const int gm0 = m0 + wm * 128;
  const int gn0 = n0 + wn * 96;
#pragma unroll
  for (int mf = 0; mf < 8; ++mf) {
#pragma unroll
    for (int nf = 0; nf < 6; ++nf) {
      const int gn = gn0 + nf * 16 + (lane & 15);
      const int tm0 = gm0 + mf * 16 + (lane >> 4) * 4;
      const float bv = bias[gn];
      const int which = gn >> 10;  // 0=Q 1=K 2=V
      const int nn = gn & 1023;
      const int h = nn >> 6, d = nn & 63;
      const int t0 = tm0 & 2047, b = tm0 >> 11;
      const int bh = b * 16 + h;
      if (which == 2) {
        h4_t pack;
#pragma unroll
        for (int r = 0; r < 4; ++r) pack[r] = (_Float16)(acc[mf][nf][r] + bv);
        *reinterpret_cast<h4_t*>(&outV[((size_t)bh * 64 + d) * 2048 + t0]) = pack;
      } else {
        _Float16* dst = (which == 0) ? outQ : outK;
        // Q pre-scaled by log2(e)/sqrt(D) so attention can use exp2 directly
        const float scale = (which == 0) ? 0.18033688011112042f : 1.0f;
#pragma unroll
        for (int r = 0; r < 4; ++r)
          dst[((size_t)bh * 2048 + t0 + r) * 64 + d] = (_Float16)((acc[mf][nf][r] + bv) * scale);
      }
    }
  }
}

// ---------------- out-proj GEMM (R8-proven) ----------------
__global__ __launch_bounds__(256, 3) void gemm_out_kernel(
    const _Float16* __restrict__ A, const _Float16* __restrict__ Bt,
    const float* __restrict__ bias, float* __restrict__ outF, int NB) {
  __shared__ _Float16 Al[3][4096];
  __shared__ _Float16 Bl[3][4096];
  const int tid = threadIdx.x;
  const int lane = tid & 63;
  const int w = tid >> 6;
  const int bm = blockIdx.x / NB;
  const int bn = blockIdx.x % NB;
  const int wm = w & 1, wn = w >> 1;
  const int m0 = bm * 128, n0 = bn * 128;

  f32x4 acc[4][4];
#pragma unroll
  for (int m = 0; m < 4; ++m)
#pragma unroll
    for (int n = 0; n < 4; ++n) acc[m][n] = (f32x4){0.f, 0.f, 0.f, 0.f};

  const int seg0 = w * 2, seg1 = w * 2 + 1;
  const int r0s = seg0 * 16 + (lane >> 2);
  const int r1s = seg1 * 16 + (lane >> 2);
  const int c0s = ((lane & 3) ^ ((r0s >> 1) & 3)) * 8;
  const int c1s = ((lane & 3) ^ ((r1s >> 1) & 3)) * 8;
  const _Float16* aS0 = A + (size_t)(m0 + r0s) * 1024 + c0s;
  const _Float16* aS1 = A + (size_t)(m0 + r1s) * 1024 + c1s;
  const _Float16* bS0 = Bt + (size_t)(n0 + r0s) * 1024 + c0s;
  const _Float16* bS1 = Bt + (size_t)(n0 + r1s) * 1024 + c1s;
  const int d0 = seg0 * 512 + lane * 8;
  const int d1 = seg1 * 512 + lane * 8;

  auto stage = [&](int buf, int kt) {
    const int k0 = kt * 32;
    gload_lds16(aS0 + k0, &Al[buf][d0]);
    gload_lds16(bS0 + k0, &Bl[buf][d0]);
    gload_lds16(aS1 + k0, &Al[buf][d1]);
    gload_lds16(bS1 + k0, &Bl[buf][d1]);
  };

  int offA[4], offB[4];
#pragma unroll
  for (int i = 0; i < 4; ++i) {
    const int rowA = wm * 64 + i * 16 + (lane & 15);
    offA[i] = rowA * 32 + (((lane >> 4) ^ ((rowA >> 1) & 3)) * 8);
    const int rowB = wn * 64 + i * 16 + (lane & 15);
    offB[i] = rowB * 32 + (((lane >> 4) ^ ((rowB >> 1) & 3)) * 8);
  }

  stage(0, 0);
  stage(1, 1);
  asm volatile("s_waitcnt vmcnt(4)" ::: "memory");
  RAW_BAR();

  int cur = 0;
#pragma unroll 1
  for (int t = 0; t < 32; ++t) {
    int nb = cur + 2; if (nb >= 3) nb -= 3;
    if (t + 2 < 32) stage(nb, t + 2);
    const _Float16* Ab = &Al[cur][0];
    const _Float16* Bb = &Bl[cur][0];
    h8_t af[4], bf[4];
#pragma unroll
    for (int i = 0; i < 4; ++i) af[i] = *(const h8_t*)&Ab[offA[i]];
#pragma unroll
    for (int j = 0; j < 4; ++j) bf[j] = *(const h8_t*)&Bb[offB[j]];
#pragma unroll
    for (int i = 0; i < 4; ++i)
#pragma unroll
      for (int j = 0; j < 4; ++j)
        acc[i][j] = MFMA_16x16x32_F16(af[i], bf[j], acc[i][j]);
    if (t < 31) {
      if (t + 2 < 32) asm volatile("s_waitcnt vmcnt(4)" ::: "memory");
      else asm volatile("s_waitcnt vmcnt(0)" ::: "memory");
      RAW_BAR();
    }
    ++cur; if (cur == 3) cur = 0;
  }

  const int gm0 = bm * 128 + wm * 64;
  const int gn0 = bn * 128 + wn * 64;
#pragma unroll
  for (int i = 0; i < 4; ++i) {
#pragma unroll
    for (int j = 0; j < 4; ++j) {
      const int gn = gn0 + j * 16 + (lane & 15);
      const int tm0 = gm0 + i * 16 + (lane >> 4) * 4;
      const float bv = bias[gn];
#pragma unroll
      for (int r = 0; r < 4; ++r)
        outF[(size_t)(tm0 + r) * 1024 + gn] = acc[i][j][r] + bv;
    }
  }
}

// ---------------- flash attention (causal), KVBLK=128, swapped-QK in-register softmax -----
// One barrier + one softmax pass per 128 KV cols (was per 64): 17 iters/block instead of 34.
// Diagonal 128-tile index == q-group g exactly; waves 0,1 skip the fully-masked upper half.
__device__ inline void stage_kv64(const _Float16* __restrict__ Kbh, const _Float16* __restrict__ Vbh,
                                  int kt, _Float16* Kd, _Float16* Vd, int w, int lane) {
  const _Float16* Kg = Kbh + (size_t)kt * 64 * 64;
  const _Float16* Vg = Vbh + kt * 64;
#pragma unroll
  for (int c = 0; c < 2; ++c) {
    const int idx = (2 * w + c) * 64 + lane;
    const int row = idx >> 3;
    const int chs = (idx & 7) ^ (row & 7);  // pre-swizzled global source (T2 via m173)
    gload_lds16(Kg + row * 64 + chs * 8, Kd + idx * 8);
    gload_lds16(Vg + (size_t)row * 2048 + chs * 8, Vd + idx * 8);
  }
}

// pack 16 exp'd f32 into 2 PV B-fragments
__device__ inline void pack_pfrag(const float* e, h8_t* out) {
  unsigned u[8];
#pragma unroll
  for (int i = 0; i < 8; ++i) {
    auto hv = __builtin_amdgcn_cvt_pkrtz(e[2 * i], e[2 * i + 1]);
    u[i] = __builtin_bit_cast(unsigned, hv);
  }
  auto r02 = __builtin_amdgcn_permlane32_swap(u[0], u[2], false, false);
  auto r13 = __builtin_amdgcn_permlane32_swap(u[1], u[3], false, false);
  auto r46 = __builtin_amdgcn_permlane32_swap(u[4], u[6], false, false);
  auto r57 = __builtin_amdgcn_permlane32_swap(u[5], u[7], false, false);
  u32x4 w0 = {(unsigned)r02[0], (unsigned)r13[0], (unsigned)r02[1], (unsigned)r13[1]};
  u32x4 w1 = {(unsigned)r46[0], (unsigned)r57[0], (unsigned)r46[1], (unsigned)r57[1]};
  out[0] = __builtin_bit_cast(h8_t, w0);
  out[1] = __builtin_bit_cast(h8_t, w1);
}

__global__ __launch_bounds__(256, 2) void attn_kernel(
    const _Float16* __restrict__ Q, const _Float16* __restrict__ K,
    const _Float16* __restrict__ Vt, _Float16* __restrict__ O) {
  __shared__ _Float16 Kl[2][2][64 * 64];  // [buf][half]
  __shared__ _Float16 Vl[2][2][64 * 64];
  const int tid = threadIdx.x;
  const int lane = tid & 63;
  const int w = tid >> 6;
  const int hi = lane >> 5;
  const int l31 = lane & 31;
  const int bh = blockIdx.x >> 3;
  const int pr = blockIdx.x & 7;
  const int b = bh >> 4, h = bh & 15;
  const _Float16* Kbh = K + (size_t)bh * 2048 * 64;
  const _Float16* Vbh = Vt + (size_t)bh * 64 * 2048;

#pragma unroll
  for (int gi = 0; gi < 2; ++gi) {
    const int g = gi ? (15 - pr) : pr;
    const int nT = g + 1;  // 128-wide KV tiles
    const int qbase = g * 128 + w * 32;
    const int qrow = qbase + l31;

    h8_t qf[4];
    const _Float16* Qp = Q + ((size_t)bh * 2048 + qrow) * 64 + hi * 8;
#pragma unroll
    for (int ds = 0; ds < 4; ++ds)
      qf[ds] = *reinterpret_cast<const h8_t*>(Qp + ds * 16);

    f32x16 oa[2] = {};
    float m = -1e30f, lsum = 0.f;

    stage_kv64(Kbh, Vbh, 0, &Kl[0][0][0], &Vl[0][0][0], w, lane);
    stage_kv64(Kbh, Vbh, 1, &Kl[0][1][0], &Vl[0][1][0], w, lane);
    __syncthreads();

#pragma unroll 1
    for (int T = 0; T < nT; ++T) {
      const int cur = T & 1;
      if (T + 1 < nT) {
        stage_kv64(Kbh, Vbh, 2 * (T + 1), &Kl[cur ^ 1][0][0], &Vl[cur ^ 1][0][0], w, lane);
        stage_kv64(Kbh, Vbh, 2 * (T + 1) + 1, &Kl[cur ^ 1][1][0], &Vl[cur ^ 1][1][0], w, lane);
      }

      const bool diag = (T == g);
      const bool skip1 = diag && (w < 2);  // upper half fully above diagonal for waves 0,1
      f32x16 s[2][2];

      // ---- QK^T (swapped): s[half][sub], col = q = l31, row = k
#pragma unroll
      for (int half = 0; half < 2; ++half) {
        if (half == 1 && skip1) {
#pragma unroll
          for (int r = 0; r < 16; ++r) { s[1][0][r] = -1e30f; s[1][1][r] = -1e30f; }
        } else {
          const char* Kb = (const char*)&Kl[cur][half][0];
          f32x16 a0 = {}, a1 = {};
#pragma unroll
          for (int ds = 0; ds < 4; ++ds) {
            const int bc = ds * 32 + hi * 16;
            h8_t kf0 = *(const h8_t*)(Kb + l31 * 128 + (bc ^ ((l31 & 7) << 4)));
            h8_t kf1 = *(const h8_t*)(Kb + (32 + l31) * 128 + (bc ^ ((l31 & 7) << 4)));
            a0 = MFMA_32x32x16_F16(kf0, qf[ds], a0);
            a1 = MFMA_32x32x16_F16(kf1, qf[ds], a1);
          }
          s[half][0] = a0;
          s[half][1] = a1;
        }
      }
      if (diag) {  // mask k > q within the diagonal 128-tile
#pragma unroll
        for (int half = 0; half < 2; ++half) {
          if (half == 1 && skip1) continue;
#pragma unroll
          for (int r = 0; r < 16; ++r) {
            const int kr = T * 128 + half * 64 + (r & 3) + 8 * (r >> 2) + 4 * hi;
            if (kr > qrow) s[half][0][r] = -1e30f;
            if (kr + 32 > qrow) s[half][1][r] = -1e30f;
          }
        }
      }

      // ---- one softmax pass over 128 cols
      float t[16];
#pragma unroll
      for (int r = 0; r < 16; ++r)
        t[r] = fmaxf(fmaxf(s[0][0][r], s[0][1][r]), fmaxf(s[1][0][r], s[1][1][r]));
#pragma unroll
      for (int st = 8; st >= 1; st >>= 1)
#pragma unroll
        for (int r = 0; r < st; ++r) t[r] = fmaxf(t[r], t[r + st]);
      const float pmax = fmaxf(t[0], __shfl_xor(t[0], 32));
      const float mnew = fmaxf(m, pmax);
      if (__any(mnew > m + 8.f)) {  // defer-max (T13)
        const float al = __builtin_amdgcn_exp2f(m - mnew);
        lsum *= al;
#pragma unroll
        for (int r = 0; r < 16; ++r) { oa[0][r] *= al; oa[1][r] *= al; }
        m = mnew;
      }
      float ps = 0.f;
#pragma unroll
      for (int half = 0; half < 2; ++half)
#pragma unroll
        for (int sub = 0; sub < 2; ++sub)
#pragma unroll
          for (int r = 0; r < 16; ++r) {
            const float pv = __builtin_amdgcn_exp2f(s[half][sub][r] - m);
            s[half][sub][r] = pv;
            ps += pv;
          }
      ps += __shfl_xor(ps, 32);
      lsum += ps;

      // ---- P -> f16 fragments in-register (T12), then PV per half
#pragma unroll
      for (int half = 0; half < 2; ++half) {
        if (half == 1 && skip1) continue;
        h8_t pf[4];
        pack_pfrag((const float*)&s[half][0], pf + 0);
        pack_pfrag((const float*)&s[half][1], pf + 2);
        const char* Vb = (const char*)&Vl[cur][half][0];
#pragma unroll
        for (int dt = 0; dt < 2; ++dt) {
#pragma unroll
          for (int kg = 0; kg < 4; ++kg) {
            const int row = dt * 32 + l31;
            const int bc = kg * 32 + hi * 16;
            h8_t vf = *(const h8_t*)(Vb + row * 128 + (bc ^ ((row & 7) << 4)));
            oa[dt] = MFMA_32x32x16_F16(vf, pf[kg], oa[dt]);
          }
        }
      }
      __syncthreads();
    }

    const float inv = __builtin_amdgcn_rcpf(lsum);
    _Float16* Op = O + ((size_t)b * 2048 + qrow) * 1024 + h * 64;
#pragma unroll
    for (int dt = 0; dt < 2; ++dt) {
#pragma unroll
      for (int rg = 0; rg < 4; ++rg) {
        h4_t pk4;
#pragma unroll
        for (int i = 0; i < 4; ++i) pk4[i] = (_Float16)(oa[dt][rg * 4 + i] * inv);
        *reinterpret_cast<h4_t*>(Op + dt * 32 + rg * 8 + hi * 4) = pk4;
      }
    }
  }
}

extern "C" void kernel_launch(void* const* d_in, const int* in_sizes, int n_in,
                              void* d_out, int out_size, void* d_ws, size_t ws_size,
                              hipStream_t stream) {
  (void)in_sizes; (void)n_in; (void)out_size; (void)ws_size;
  const float* x = (const float*)d_in[0];
  const float* w_qkv = (const float*)d_in[1];
  const float* b_qkv = (const float*)d_in[2];
  const float* w_out = (const float*)d_in[3];
  const float* b_out = (const float*)d_in[4];
  float* out = (float*)d_out;

  char* ws = (char*)d_ws;
  size_t off = 0;
  auto alloc = [&](size_t bytes) {
    void* p = ws + off;
    off += (bytes + 255) & ~(size_t)255;
    return p;
  };
  _Float16* x16 = (_Float16*)alloc((size_t)8192 * 1024 * 2);
  _Float16* wqkvT = (_Float16*)alloc((size_t)3072 * 1024 * 2);
  _Float16* woutT = (_Float16*)alloc((size_t)1024 * 1024 * 2);
  _Float16* Qh = (_Float16*)alloc((size_t)64 * 2048 * 64 * 2);
  _Float16* Kh = (_Float16*)alloc((size_t)64 * 2048 * 64 * 2);
  _Float16* Vth = (_Float16*)alloc((size_t)64 * 64 * 2048 * 2);
  _Float16* Oh = (_Float16*)alloc((size_t)8192 * 1024 * 2);

  cvt_f16_kernel<<<8192, 256, 0, stream>>>(x, x16, 8192 * 1024 / 4);
  transpose_cvt_kernel<<<dim3(3072 / 32, 1024 / 32), 256, 0, stream>>>(w_qkv, wqkvT, 1024, 3072);
  transpose_cvt_kernel<<<dim3(1024 / 32, 1024 / 32), 256, 0, stream>>>(w_out, woutT, 1024, 1024);
  gemm_qkv_kernel<<<256, 512, 0, stream>>>(x16, wqkvT, b_qkv, Qh, Kh, Vth);
  attn_kernel<<<64 * 8, 256, 0, stream>>>(Qh, Kh, Vth, Oh);
  gemm_out_kernel<<<64 * 8, 256, 0, stream>>>(Oh, woutT, b_out, out, 8);
}

// Round 11
// 171.479 us; speedup vs baseline: 1.2578x; 1.0359x over previous
//
#include <hip/hip_runtime.h>
#include <cstdint>
#include <cstddef>

typedef _Float16 h8_t __attribute__((ext_vector_type(8)));
typedef _Float16 h4_t __attribute__((ext_vector_type(4)));
typedef float f32x4 __attribute__((ext_vector_type(4)));
typedef float f32x16 __attribute__((ext_vector_type(16)));
typedef unsigned u32x4 __attribute__((ext_vector_type(4)));

#define MFMA_16x16x32_F16(a, b, c) __builtin_amdgcn_mfma_f32_16x16x32_f16(a, b, c, 0, 0, 0)
#define MFMA_32x32x16_F16(a, b, c) __builtin_amdgcn_mfma_f32_32x32x16_f16(a, b, c, 0, 0, 0)

__device__ inline void gload_lds16(const void* g, void* l) {
  __builtin_amdgcn_global_load_lds((const __attribute__((address_space(1))) void*)g,
                                   (__attribute__((address_space(3))) void*)l, 16, 0, 0);
}

#define CFENCE asm volatile("" ::: "memory")
#define RAW_BAR() do { CFENCE; __builtin_amdgcn_s_barrier(); CFENCE; } while (0)

// ---------------- convert f32 -> f16 ----------------
__global__ void cvt_f16_kernel(const float* __restrict__ in, _Float16* __restrict__ out, int n4) {
  int i = blockIdx.x * 256 + threadIdx.x;
  if (i >= n4) return;
  float4 v = reinterpret_cast<const float4*>(in)[i];
  h4_t h;
  h[0] = (_Float16)v.x; h[1] = (_Float16)v.y; h[2] = (_Float16)v.z; h[3] = (_Float16)v.w;
  reinterpret_cast<h4_t*>(out)[i] = h;
}

// ---------------- transpose + convert: in[R][Cc] f32 -> out[Cc][R] f16 ----------------
__global__ void transpose_cvt_kernel(const float* __restrict__ in, _Float16* __restrict__ out,
                                     int R, int Cc) {
  __shared__ float tile[32][33];
  int tx = threadIdx.x & 31;
  int ty = threadIdx.x >> 5;
  int c0 = blockIdx.x * 32;
  int r0 = blockIdx.y * 32;
#pragma unroll
  for (int i = 0; i < 4; ++i)
    tile[ty + i * 8][tx] = in[(size_t)(r0 + ty + i * 8) * Cc + (c0 + tx)];
  __syncthreads();
#pragma unroll
  for (int i = 0; i < 4; ++i)
    out[(size_t)(c0 + ty + i * 8) * R + (r0 + tx)] = (_Float16)tile[tx][ty + i * 8];
}

// ============ QKV GEMM (R9, kept): 256x384 tile, 8 waves, 2-phase/K-tile, triple-buffer ===
__global__ __launch_bounds__(512, 2) void gemm_qkv_kernel(
    const _Float16* __restrict__ A, const _Float16* __restrict__ Bt,
    const float* __restrict__ bias, _Float16* __restrict__ outQ,
    _Float16* __restrict__ outK, _Float16* __restrict__ outV) {
  __shared__ _Float16 Al[3][8192];
  __shared__ _Float16 Bl[3][12288];

  const int tid = threadIdx.x;
  const int lane = tid & 63;
  const int w = tid >> 6;
  const int wm = w >> 2, wn = w & 3;
  const int bm = blockIdx.x >> 3;
  const int bn = blockIdx.x & 7;
  const int m0 = bm * 256;
  const int n0 = bn * 384;

  f32x4 acc[8][6];
#pragma unroll
  for (int i = 0; i < 8; ++i)
#pragma unroll
    for (int j = 0; j < 6; ++j) acc[i][j] = (f32x4){0.f, 0.f, 0.f, 0.f};

  const int fg0 = tid >> 6;
  const int sl = tid & 63;
  const int srow = fg0 * 16 + (sl & 15);
  const int scol = (sl >> 4) * 8;
  const _Float16* aS = A + (size_t)(m0 + srow) * 1024 + scol;
  const _Float16* bS = Bt + (size_t)(n0 + srow) * 1024 + scol;
  const int sdst = tid * 8;

  auto stageA = [&](int buf, int kt) {
    const int k0 = kt * 32;
    gload_lds16(aS + k0, &Al[buf][sdst]);
    gload_lds16(aS + 131072 + k0, &Al[buf][sdst + 4096]);
  };
  auto stageB = [&](int buf, int kt) {
    const int k0 = kt * 32;
    gload_lds16(bS + k0, &Bl[buf][sdst]);
    gload_lds16(bS + 131072 + k0, &Bl[buf][sdst + 4096]);
    gload_lds16(bS + 262144 + k0, &Bl[buf][sdst + 8192]);
  };

  const int offA0 = (wm * 8 * 64 + lane) * 8;
  const int offB0 = (wn * 6 * 64 + lane) * 8;

  stageA(0, 0); stageB(0, 0);
  stageA(1, 1); stageB(1, 1);
  asm volatile("s_waitcnt vmcnt(5)" ::: "memory");
  RAW_BAR();

  int cur = 0;
#pragma unroll 1
  for (int t = 0; t < 32; ++t) {
    int nb = cur + 2; if (nb >= 3) nb -= 3;
    const bool st = (t + 2) < 32;
    const _Float16* Ab = &Al[cur][0];
    const _Float16* Bb = &Bl[cur][0];
    h8_t af[4], bf[6];

#pragma unroll
    for (int mf = 0; mf < 4; ++mf) af[mf] = *(const h8_t*)&Ab[offA0 + mf * 512];
#pragma unroll
    for (int nf = 0; nf < 6; ++nf) bf[nf] = *(const h8_t*)&Bb[offB0 + nf * 512];
    if (st) stageA(nb, t + 2);
    RAW_BAR();
    asm volatile("s_waitcnt lgkmcnt(0)" ::: "memory");
    __builtin_amdgcn_sched_barrier(0);
    __builtin_amdgcn_s_setprio(1);
#pragma unroll
    for (int mf = 0; mf < 4; ++mf)
#pragma unroll
      for (int nf = 0; nf < 6; ++nf)
        acc[mf][nf] = MFMA_16x16x32_F16(af[mf], bf[nf], acc[mf][nf]);
    __builtin_amdgcn_s_setprio(0);
    RAW_BAR();

#pragma unroll
    for (int mf = 0; mf < 4; ++mf) af[mf] = *(const h8_t*)&Ab[offA0 + (4 + mf) * 512];
    if (st) stageB(nb, t + 2);
    RAW_BAR();
    asm volatile("s_waitcnt lgkmcnt(0)" ::: "memory");
    __builtin_amdgcn_sched_barrier(0);
    __builtin_amdgcn_s_setprio(1);
#pragma unroll
    for (int mf = 0; mf < 4; ++mf)
#pragma unroll
      for (int nf = 0; nf < 6; ++nf)
        acc[4 + mf][nf] = MFMA_16x16x32_F16(af[mf], bf[nf], acc[4 + mf][nf]);
    __builtin_amdgcn_s_setprio(0);
    if (t < 31) {
      if (st) asm volatile("s_waitcnt vmcnt(5)" ::: "memory");
      else asm volatile("s_waitcnt vmcnt(0)" ::: "memory");
      RAW_BAR();
    }
    ++cur; if (cur == 3) cur = 0;
  }

  const int gm0 = m0 + wm * 128;
  const int gn0 = n0 + wn * 96;
#pragma unroll
  for (int mf = 0; mf < 8; ++mf) {
#pragma unroll
    for (int nf = 0; nf < 6; ++nf) {
      const int gn = gn0 + nf * 16 + (lane & 15);
      const int tm0 = gm0 + mf * 16 + (lane >> 4) * 4;
      const float bv = bias[gn];
      const int which = gn >> 10;  // 0=Q 1=K 2=V
      const int nn = gn & 1023;
      const int h = nn >> 6, d = nn & 63;
      const int t0 = tm0 & 2047, b = tm0 >> 11;
      const int bh = b * 16 + h;
      if (which == 2) {
        h4_t pack;
#pragma unroll
        for (int r = 0; r < 4; ++r) pack[r] = (_Float16)(acc[mf][nf][r] + bv);
        *reinterpret_cast<h4_t*>(&outV[((size_t)bh * 64 + d) * 2048 + t0]) = pack;
      } else {
        _Float16* dst = (which == 0) ? outQ : outK;
        // Q pre-scaled by log2(e)/sqrt(D) so attention can use exp2 directly
        const float scale = (which == 0) ? 0.18033688011112042f : 1.0f;
#pragma unroll
        for (int r = 0; r < 4; ++r)
          dst[((size_t)bh * 2048 + t0 + r) * 64 + d] = (_Float16)((acc[mf][nf][r] + bv) * scale);
      }
    }
  }
}

// ---------------- out-proj GEMM (R8-proven) ----------------
__global__ __launch_bounds__(256, 3) void gemm_out_kernel(
    const _Float16* __restrict__ A, const _Float16* __restrict__ Bt,
    const float* __restrict__ bias, float* __restrict__ outF, int NB) {
  __shared__ _Float16 Al[3][4096];
  __shared__ _Float16 Bl[3][4096];
  const int tid = threadIdx.x;
  const int lane = tid & 63;
  const int w = tid >> 6;
  const int bm = blockIdx.x / NB;
  const int bn = blockIdx.x % NB;
  const int wm = w & 1, wn = w >> 1;
  const int m0 = bm * 128, n0 = bn * 128;

  f32x4 acc[4][4];
#pragma unroll
  for (int m = 0; m < 4; ++m)
#pragma unroll
    for (int n = 0; n < 4; ++n) acc[m][n] = (f32x4){0.f, 0.f, 0.f, 0.f};

  const int seg0 = w * 2, seg1 = w * 2 + 1;
  const int r0s = seg0 * 16 + (lane >> 2);
  const int r1s = seg1 * 16 + (lane >> 2);
  const int c0s = ((lane & 3) ^ ((r0s >> 1) & 3)) * 8;
  const int c1s = ((lane & 3) ^ ((r1s >> 1) & 3)) * 8;
  const _Float16* aS0 = A + (size_t)(m0 + r0s) * 1024 + c0s;
  const _Float16* aS1 = A + (size_t)(m0 + r1s) * 1024 + c1s;
  const _Float16* bS0 = Bt + (size_t)(n0 + r0s) * 1024 + c0s;
  const _Float16* bS1 = Bt + (size_t)(n0 + r1s) * 1024 + c1s;
  const int d0 = seg0 * 512 + lane * 8;
  const int d1 = seg1 * 512 + lane * 8;

  auto stage = [&](int buf, int kt) {
    const int k0 = kt * 32;
    gload_lds16(aS0 + k0, &Al[buf][d0]);
    gload_lds16(bS0 + k0, &Bl[buf][d0]);
    gload_lds16(aS1 + k0, &Al[buf][d1]);
    gload_lds16(bS1 + k0, &Bl[buf][d1]);
  };

  int offA[4], offB[4];
#pragma unroll
  for (int i = 0; i < 4; ++i) {
    const int rowA = wm * 64 + i * 16 + (lane & 15);
    offA[i] = rowA * 32 + (((lane >> 4) ^ ((rowA >> 1) & 3)) * 8);
    const int rowB = wn * 64 + i * 16 + (lane & 15);
    offB[i] = rowB * 32 + (((lane >> 4) ^ ((rowB >> 1) & 3)) * 8);
  }

  stage(0, 0);
  stage(1, 1);
  asm volatile("s_waitcnt vmcnt(4)" ::: "memory");
  RAW_BAR();

  int cur = 0;
#pragma unroll 1
  for (int t = 0; t < 32; ++t) {
    int nb = cur + 2; if (nb >= 3) nb -= 3;
    if (t + 2 < 32) stage(nb, t + 2);
    const _Float16* Ab = &Al[cur][0];
    const _Float16* Bb = &Bl[cur][0];
    h8_t af[4], bf[4];
#pragma unroll
    for (int i = 0; i < 4; ++i) af[i] = *(const h8_t*)&Ab[offA[i]];
#pragma unroll
    for (int j = 0; j < 4; ++j) bf[j] = *(const h8_t*)&Bb[offB[j]];
#pragma unroll
    for (int i = 0; i < 4; ++i)
#pragma unroll
      for (int j = 0; j < 4; ++j)
        acc[i][j] = MFMA_16x16x32_F16(af[i], bf[j], acc[i][j]);
    if (t < 31) {
      if (t + 2 < 32) asm volatile("s_waitcnt vmcnt(4)" ::: "memory");
      else asm volatile("s_waitcnt vmcnt(0)" ::: "memory");
      RAW_BAR();
    }
    ++cur; if (cur == 3) cur = 0;
  }

  const int gm0 = bm * 128 + wm * 64;
  const int gn0 = bn * 128 + wn * 64;
#pragma unroll
  for (int i = 0; i < 4; ++i) {
#pragma unroll
    for (int j = 0; j < 4; ++j) {
      const int gn = gn0 + j * 16 + (lane & 15);
      const int tm0 = gm0 + i * 16 + (lane >> 4) * 4;
      const float bv = bias[gn];
#pragma unroll
      for (int r = 0; r < 4; ++r)
        outF[(size_t)(tm0 + r) * 1024 + gn] = acc[i][j][r] + bv;
    }
  }
}

// ---------------- flash attention (causal), KVBLK=128, swapped-QK in-register softmax -----
// bh-locality block mapping: bh = blk & 63, pr = blk >> 6 => blk % 8 == bh % 8, so all 8
// q-group blocks of one (b,h) land on ONE XCD and each bh lives on exactly one XCD ->
// K/V fetched from HBM once per bh (was ~8 XCDs x per-bh refetch). Per-XCD L2 working
// set = 8 bh x 512 KB = 4 MB.
__device__ inline void stage_kv64(const _Float16* __restrict__ Kbh, const _Float16* __restrict__ Vbh,
                                  int kt, _Float16* Kd, _Float16* Vd, int w, int lane) {
  const _Float16* Kg = Kbh + (size_t)kt * 64 * 64;
  const _Float16* Vg = Vbh + kt * 64;
#pragma unroll
  for (int c = 0; c < 2; ++c) {
    const int idx = (2 * w + c) * 64 + lane;
    const int row = idx >> 3;
    const int chs = (idx & 7) ^ (row & 7);  // pre-swizzled global source (T2 via m173)
    gload_lds16(Kg + row * 64 + chs * 8, Kd + idx * 8);
    gload_lds16(Vg + (size_t)row * 2048 + chs * 8, Vd + idx * 8);
  }
}

// pack 16 exp'd f32 into 2 PV B-fragments
__device__ inline void pack_pfrag(const float* e, h8_t* out) {
  unsigned u[8];
#pragma unroll
  for (int i = 0; i < 8; ++i) {
    auto hv = __builtin_amdgcn_cvt_pkrtz(e[2 * i], e[2 * i + 1]);
    u[i] = __builtin_bit_cast(unsigned, hv);
  }
  auto r02 = __builtin_amdgcn_permlane32_swap(u[0], u[2], false, false);
  auto r13 = __builtin_amdgcn_permlane32_swap(u[1], u[3], false, false);
  auto r46 = __builtin_amdgcn_permlane32_swap(u[4], u[6], false, false);
  auto r57 = __builtin_amdgcn_permlane32_swap(u[5], u[7], false, false);
  u32x4 w0 = {(unsigned)r02[0], (unsigned)r13[0], (unsigned)r02[1], (unsigned)r13[1]};
  u32x4 w1 = {(unsigned)r46[0], (unsigned)r57[0], (unsigned)r46[1], (unsigned)r57[1]};
  out[0] = __builtin_bit_cast(h8_t, w0);
  out[1] = __builtin_bit_cast(h8_t, w1);
}

__global__ __launch_bounds__(256, 2) void attn_kernel(
    const _Float16* __restrict__ Q, const _Float16* __restrict__ K,
    const _Float16* __restrict__ Vt, _Float16* __restrict__ O) {
  __shared__ _Float16 Kl[2][2][64 * 64];  // [buf][half]
  __shared__ _Float16 Vl[2][2][64 * 64];
  const int tid = threadIdx.x;
  const int lane = tid & 63;
  const int w = tid >> 6;
  const int hi = lane >> 5;
  const int l31 = lane & 31;
  const int bh = blockIdx.x & 63;   // bh-locality: all pr of a bh share one XCD
  const int pr = blockIdx.x >> 6;
  const int b = bh >> 4, h = bh & 15;
  const _Float16* Kbh = K + (size_t)bh * 2048 * 64;
  const _Float16* Vbh = Vt + (size_t)bh * 64 * 2048;

#pragma unroll
  for (int gi = 0; gi < 2; ++gi) {
    const int g = gi ? (15 - pr) : pr;
    const int nT = g + 1;  // 128-wide KV tiles
    const int qbase = g * 128 + w * 32;
    const int qrow = qbase + l31;

    h8_t qf[4];
    const _Float16* Qp = Q + ((size_t)bh * 2048 + qrow) * 64 + hi * 8;
#pragma unroll
    for (int ds = 0; ds < 4; ++ds)
      qf[ds] = *reinterpret_cast<const h8_t*>(Qp + ds * 16);

    f32x16 oa[2] = {};
    float m = -1e30f, lsum = 0.f;

    stage_kv64(Kbh, Vbh, 0, &Kl[0][0][0], &Vl[0][0][0], w, lane);
    stage_kv64(Kbh, Vbh, 1, &Kl[0][1][0], &Vl[0][1][0], w, lane);
    __syncthreads();

#pragma unroll 1
    for (int T = 0; T < nT; ++T) {
      const int cur = T & 1;
      if (T + 1 < nT) {
        stage_kv64(Kbh, Vbh, 2 * (T + 1), &Kl[cur ^ 1][0][0], &Vl[cur ^ 1][0][0], w, lane);
        stage_kv64(Kbh, Vbh, 2 * (T + 1) + 1, &Kl[cur ^ 1][1][0], &Vl[cur ^ 1][1][0], w, lane);
      }

      const bool diag = (T == g);
      const bool skip1 = diag && (w < 2);  // upper half fully above diagonal for waves 0,1
      f32x16 s[2][2];

      // ---- QK^T (swapped): s[half][sub], col = q = l31, row = k
#pragma unroll
      for (int half = 0; half < 2; ++half) {
        if (half == 1 && skip1) {
#pragma unroll
          for (int r = 0; r < 16; ++r) { s[1][0][r] = -1e30f; s[1][1][r] = -1e30f; }
        } else {
          const char* Kb = (const char*)&Kl[cur][half][0];
          f32x16 a0 = {}, a1 = {};
#pragma unroll
          for (int ds = 0; ds < 4; ++ds) {
            const int bc = ds * 32 + hi * 16;
            h8_t kf0 = *(const h8_t*)(Kb + l31 * 128 + (bc ^ ((l31 & 7) << 4)));
            h8_t kf1 = *(const h8_t*)(Kb + (32 + l31) * 128 + (bc ^ ((l31 & 7) << 4)));
            a0 = MFMA_32x32x16_F16(kf0, qf[ds], a0);
            a1 = MFMA_32x32x16_F16(kf1, qf[ds], a1);
          }
          s[half][0] = a0;
          s[half][1] = a1;
        }
      }
      if (diag) {  // mask k > q within the diagonal 128-tile
#pragma unroll
        for (int half = 0; half < 2; ++half) {
          if (half == 1 && skip1) continue;
#pragma unroll
          for (int r = 0; r < 16; ++r) {
            const int kr = T * 128 + half * 64 + (r & 3) + 8 * (r >> 2) + 4 * hi;
            if (kr > qrow) s[half][0][r] = -1e30f;
            if (kr + 32 > qrow) s[half][1][r] = -1e30f;
          }
        }
      }

      // ---- one softmax pass over 128 cols
      float t[16];
#pragma unroll
      for (int r = 0; r < 16; ++r)
        t[r] = fmaxf(fmaxf(s[0][0][r], s[0][1][r]), fmaxf(s[1][0][r], s[1][1][r]));
#pragma unroll
      for (int st = 8; st >= 1; st >>= 1)
#pragma unroll
        for (int r = 0; r < st; ++r) t[r] = fmaxf(t[r], t[r + st]);
      const float pmax = fmaxf(t[0], __shfl_xor(t[0], 32));
      const float mnew = fmaxf(m, pmax);
      if (__any(mnew > m + 8.f)) {  // defer-max (T13)
        const float al = __builtin_amdgcn_exp2f(m - mnew);
        lsum *= al;
#pragma unroll
        for (int r = 0; r < 16; ++r) { oa[0][r] *= al; oa[1][r] *= al; }
        m = mnew;
      }
      float ps = 0.f;
#pragma unroll
      for (int half = 0; half < 2; ++half)
#pragma unroll
        for (int sub = 0; sub < 2; ++sub)
#pragma unroll
          for (int r = 0; r < 16; ++r) {
            const float pv = __builtin_amdgcn_exp2f(s[half][sub][r] - m);
            s[half][sub][r] = pv;
            ps += pv;
          }
      ps += __shfl_xor(ps, 32);
      lsum += ps;

      // ---- P -> f16 fragments in-register (T12), then PV per half
#pragma unroll
      for (int half = 0; half < 2; ++half) {
        if (half == 1 && skip1) continue;
        h8_t pf[4];
        pack_pfrag((const float*)&s[half][0], pf + 0);
        pack_pfrag((const float*)&s[half][1], pf + 2);
        const char* Vb = (const char*)&Vl[cur][half][0];
#pragma unroll
        for (int dt = 0; dt < 2; ++dt) {
#pragma unroll
          for (int kg = 0; kg < 4; ++kg) {
            const int row = dt * 32 + l31;
            const int bc = kg * 32 + hi * 16;
            h8_t vf = *(const h8_t*)(Vb + row * 128 + (bc ^ ((row & 7) << 4)));
            oa[dt] = MFMA_32x32x16_F16(vf, pf[kg], oa[dt]);
          }
        }
      }
      __syncthreads();
    }

    const float inv = __builtin_amdgcn_rcpf(lsum);
    _Float16* Op = O + ((size_t)b * 2048 + qrow) * 1024 + h * 64;
#pragma unroll
    for (int dt = 0; dt < 2; ++dt) {
#pragma unroll
      for (int rg = 0; rg < 4; ++rg) {
        h4_t pk4;
#pragma unroll
        for (int i = 0; i < 4; ++i) pk4[i] = (_Float16)(oa[dt][rg * 4 + i] * inv);
        *reinterpret_cast<h4_t*>(Op + dt * 32 + rg * 8 + hi * 4) = pk4;
      }
    }
  }
}

extern "C" void kernel_launch(void* const* d_in, const int* in_sizes, int n_in,
                              void* d_out, int out_size, void* d_ws, size_t ws_size,
                              hipStream_t stream) {
  (void)in_sizes; (void)n_in; (void)out_size; (void)ws_size;
  const float* x = (const float*)d_in[0];
  const float* w_qkv = (const float*)d_in[1];
  const float* b_qkv = (const float*)d_in[2];
  const float* w_out = (const float*)d_in[3];
  const float* b_out = (const float*)d_in[4];
  float* out = (float*)d_out;

  char* ws = (char*)d_ws;
  size_t off = 0;
  auto alloc = [&](size_t bytes) {
    void* p = ws + off;
    off += (bytes + 255) & ~(size_t)255;
    return p;
  };
  _Float16* x16 = (_Float16*)alloc((size_t)8192 * 1024 * 2);
  _Float16* wqkvT = (_Float16*)alloc((size_t)3072 * 1024 * 2);
  _Float16* woutT = (_Float16*)alloc((size_t)1024 * 1024 * 2);
  _Float16* Qh = (_Float16*)alloc((size_t)64 * 2048 * 64 * 2);
  _Float16* Kh = (_Float16*)alloc((size_t)64 * 2048 * 64 * 2);
  _Float16* Vth = (_Float16*)alloc((size_t)64 * 64 * 2048 * 2);
  _Float16* Oh = (_Float16*)alloc((size_t)8192 * 1024 * 2);

  cvt_f16_kernel<<<8192, 256, 0, stream>>>(x, x16, 8192 * 1024 / 4);
  transpose_cvt_kernel<<<dim3(3072 / 32, 1024 / 32), 256, 0, stream>>>(w_qkv, wqkvT, 1024, 3072);
  transpose_cvt_kernel<<<dim3(1024 / 32, 1024 / 32), 256, 0, stream>>>(w_out, woutT, 1024, 1024);
  gemm_qkv_kernel<<<256, 512, 0, stream>>>(x16, wqkvT, b_qkv, Qh, Kh, Vth);
  attn_kernel<<<64 * 8, 256, 0, stream>>>(Qh, Kh, Vth, Oh);
  gemm_out_kernel<<<64 * 8, 256, 0, stream>>>(Oh, woutT, b_out, out, 8);
}